// Round 6
// baseline (403.452 us; speedup 1.0000x reference)
//
#include <hip/hip_runtime.h>

#define BB 4
#define SLQ 1024
#define SLK 2048
#define EE 512
#define HH 8
#define HD 64

typedef unsigned short u16;
typedef __attribute__((ext_vector_type(8))) short s16x8;
typedef __attribute__((ext_vector_type(4))) float f32x4;

__device__ __forceinline__ float bf2f(u16 u) {
  union { unsigned int i; float f; } v; v.i = ((unsigned int)u) << 16; return v.f;
}
__device__ __forceinline__ u16 f2bf(float f) {
  union { float f; unsigned int i; } v; v.f = f;
  unsigned int i = v.i;
  return (u16)((i + 0x7fffu + ((i >> 16) & 1u)) >> 16);
}

__device__ __forceinline__ void async16(const u16* g, u16* l) {
  __builtin_amdgcn_global_load_lds(
      (const __attribute__((address_space(1))) unsigned int*)g,
      (__attribute__((address_space(3))) unsigned int*)l, 16, 0, 0);
}

// NT GEMM: C[m,n] = alpha * sum_k A[m,k]*B[n,k] + bias[n]   (A,B bf16; bias f32)
// MODE 0: C + z*sCz row-major, LDS-staged coalesced C write
// MODE 1: head-split [B,H,Lsub,64]
// MODE 2: head-split transposed [B,H,64,Lsub], LDS-staged coalesced write
// SKIPQ 0: none; 1: b=z>>3, skip tileM>=qlen[b]; 2: b=tileM>>10 (Lsub=1024)
template<int BM, int BN, int MODE, int SKIPQ>
__global__ __launch_bounds__(256, 2)
void gemm_nt(const u16* __restrict__ A, const u16* __restrict__ Bm,
             const float* __restrict__ bias, u16* __restrict__ C,
             int M, int N, int K, int lda, int ldb, int ldc,
             long sAz, long sBz, long sCz, float alpha, int Lsub,
             const int* __restrict__ qlen)
{
  constexpr int WTM = BM / 2, WTN = BN / 2;
  constexpr int MI = WTM / 16, NI = WTN / 16;

  const int z = blockIdx.z;
  const int tileM = blockIdx.y * BM;
  const int tileN = blockIdx.x * BN;

  if (SKIPQ == 1) { if (tileM >= qlen[z >> 3]) return; }
  if (SKIPQ == 2) { int b = tileM >> 10; if ((tileM & 1023) >= qlen[b]) return; }

  __shared__ __align__(16) u16 smem[(BM + BN) * 32];
  u16* ldsA = smem;
  u16* ldsB = smem + BM * 32;

  const int t = threadIdx.x;
  const int lane = t & 63;
  const int wave = t >> 6;
  const int waveM = wave >> 1;
  const int waveN = wave & 1;
  const int lm = lane & 15;
  const int kg = lane >> 4;

  const u16* Ab = A + (long)z * sAz + (long)tileM * lda;
  const u16* Bb = Bm + (long)z * sBz + (long)tileN * ldb;

  f32x4 acc[MI][NI];
#pragma unroll
  for (int i = 0; i < MI; ++i)
#pragma unroll
    for (int j = 0; j < NI; ++j) acc[i][j] = (f32x4){0.f, 0.f, 0.f, 0.f};

  for (int kt = 0; kt < K; kt += 32) {
    __syncthreads();
#pragma unroll
    for (int i = 0; i < (BM * 4) / 256; ++i) {
      int c = i * 256 + t;
      async16(Ab + (long)(c >> 2) * lda + kt + (c & 3) * 8, ldsA + (c - lane) * 8);
    }
#pragma unroll
    for (int i = 0; i < (BN * 4) / 256; ++i) {
      int c = i * 256 + t;
      async16(Bb + (long)(c >> 2) * ldb + kt + (c & 3) * 8, ldsB + (c - lane) * 8);
    }
    __syncthreads();

    s16x8 aF[MI], bF[NI];
#pragma unroll
    for (int i = 0; i < MI; ++i)
      aF[i] = *(const s16x8*)&ldsA[(waveM * WTM + i * 16 + lm) * 32 + kg * 8];
#pragma unroll
    for (int j = 0; j < NI; ++j)
      bF[j] = *(const s16x8*)&ldsB[(waveN * WTN + j * 16 + lm) * 32 + kg * 8];
#pragma unroll
    for (int i = 0; i < MI; ++i)
#pragma unroll
      for (int j = 0; j < NI; ++j)
        acc[i][j] = __builtin_amdgcn_mfma_f32_16x16x32_bf16(aF[i], bF[j], acc[i][j], 0, 0, 0);
  }

  if (MODE == 0) {
#pragma unroll
    for (int c = 0; c < BM / 32; ++c) {
      const int rlo = c * 32;
      __syncthreads();
#pragma unroll
      for (int i = 0; i < MI; ++i) {
        int mbase = waveM * WTM + i * 16;
        if (mbase >= rlo && mbase < rlo + 32) {
#pragma unroll
          for (int j = 0; j < NI; ++j) {
            int n = waveN * WTN + j * 16 + lm;
            float bv = bias ? bias[tileN + n] : 0.0f;
#pragma unroll
            for (int r = 0; r < 4; ++r) {
              int m = mbase + kg * 4 + r;
              smem[(m - rlo) * BN + n] = f2bf(acc[i][j][r] * alpha + bv);
            }
          }
        }
      }
      __syncthreads();
#pragma unroll
      for (int v = 0; v < (32 * BN) / (256 * 8); ++v) {
        int idx = v * 256 + t;
        int row = idx / (BN / 8), col8 = idx % (BN / 8);
        *(uint4*)&C[(long)z * sCz + (long)(tileM + rlo + row) * ldc + tileN + col8 * 8] =
            *(const uint4*)&smem[row * BN + col8 * 8];
      }
    }
  } else if (MODE == 2) {
    // transposed store staged through LDS: chunks of 32 n-cols, coalesced rows of BM
    constexpr int PAD = BM + 8;
    const int bb = tileM / Lsub;               // tile fully inside one b
    const int l0 = tileM - bb * Lsub;
#pragma unroll
    for (int c = 0; c < BN / 32; ++c) {
      __syncthreads();
#pragma unroll
      for (int j = 0; j < NI; ++j) {
        int nloc = waveN * WTN + j * 16 + lm;
        if (nloc >= c * 32 && nloc < c * 32 + 32) {
          int nl = nloc - c * 32;
          float bv = bias ? bias[tileN + nloc] : 0.0f;
#pragma unroll
          for (int i = 0; i < MI; ++i)
#pragma unroll
            for (int r = 0; r < 4; ++r) {
              int mm = waveM * WTM + i * 16 + kg * 4 + r;
              smem[nl * PAD + mm] = f2bf(acc[i][j][r] * alpha + bv);
            }
        }
      }
      __syncthreads();
#pragma unroll
      for (int v = 0; v < (32 * BM) / (256 * 8); ++v) {
        int idx = v * 256 + t;
        int nl = idx / (BM / 8), m8 = idx % (BM / 8);
        int n = tileN + c * 32 + nl;
        int h = n >> 6, d = n & 63;
        *(uint4*)&C[((long)(bb * HH + h) * HD + d) * Lsub + l0 + m8 * 8] =
            *(const uint4*)&smem[nl * PAD + m8 * 8];
      }
    }
  } else {
#pragma unroll
    for (int j = 0; j < NI; ++j) {
      int n = tileN + waveN * WTN + j * 16 + lm;
      float bv = bias ? bias[n] : 0.0f;
#pragma unroll
      for (int i = 0; i < MI; ++i) {
#pragma unroll
        for (int r = 0; r < 4; ++r) {
          int m = tileM + waveM * WTM + i * 16 + kg * 4 + r;
          float v = acc[i][j][r] * alpha + bv;
          int b = m / Lsub, l = m - b * Lsub;
          int h = n >> 6, d = n & 63;
          C[(((long)(b * HH + h) * Lsub + l) << 6) + d] = f2bf(v);
        }
      }
    }
  }
}

// ---------- cross attention: flash chunk (QK^T + raw-S write + online PV) ----
// grid (16 q-tiles of 64, 32 bh, 4 k-chunks of 512); inner loop 4x128 keys
__global__ __launch_bounds__(256, 2)
void cross_flash_chunk(const u16* __restrict__ Qc, const u16* __restrict__ Kc,
                       const u16* __restrict__ Vt, u16* __restrict__ S,
                       float* __restrict__ Opart, float2* __restrict__ mlc,
                       const int* __restrict__ qlen)
{
  const int qt = blockIdx.x;
  const int bh = blockIdx.y;
  const int kc = blockIdx.z;
  const int b = bh >> 3;
  if (qt * 64 >= qlen[b]) return;

  __shared__ __align__(16) u16 Kt[128 * 72];
  __shared__ __align__(16) u16 Vl[64 * 136];
  __shared__ __align__(16) u16 Pl[4 * 16 * 136];
  __shared__ __align__(16) u16 Sr[64 * 136];

  const int t = threadIdx.x, lane = t & 63, w = t >> 6;
  const int col = lane & 15, quad = lane >> 4;

  const u16* Qb = Qc + (long)bh * SLQ * HD;
  const u16* Kb = Kc + (long)bh * SLK * HD;
  const u16* Vb = Vt + (long)bh * HD * SLK;

  s16x8 aQ[2];
#pragma unroll
  for (int kk = 0; kk < 2; ++kk)
    aQ[kk] = *(const s16x8*)(Qb + (long)(qt * 64 + w * 16 + col) * HD + kk * 32 + quad * 8);

  f32x4 O[4];
  float mr[4], lr[4];
#pragma unroll
  for (int n = 0; n < 4; ++n) O[n] = (f32x4){0.f, 0.f, 0.f, 0.f};
#pragma unroll
  for (int r = 0; r < 4; ++r) { mr[r] = -1e30f; lr[r] = 0.f; }

  u16* Pw = Pl + w * 16 * 136;

  for (int ks = 0; ks < 4; ++ks) {
    const int k0 = kc * 512 + ks * 128;
    __syncthreads();
    for (int c = t; c < 1024; c += 256) {
      int r = c >> 3, c8 = c & 7;
      *(uint4*)&Kt[r * 72 + c8 * 8] = *(const uint4*)(Kb + (long)(k0 + r) * HD + c8 * 8);
    }
    for (int c = t; c < 1024; c += 256) {
      int d = c >> 4, c16 = c & 15;
      *(uint4*)&Vl[d * 136 + c16 * 8] = *(const uint4*)(Vb + (long)d * SLK + k0 + c16 * 8);
    }
    __syncthreads();

    f32x4 s[8];
#pragma unroll
    for (int j = 0; j < 8; ++j) s[j] = (f32x4){0.f, 0.f, 0.f, 0.f};
#pragma unroll
    for (int j = 0; j < 8; ++j)
#pragma unroll
      for (int kk = 0; kk < 2; ++kk) {
        s16x8 bK = *(const s16x8*)&Kt[(j * 16 + col) * 72 + kk * 32 + quad * 8];
        s[j] = __builtin_amdgcn_mfma_f32_16x16x32_bf16(aQ[kk], bK, s[j], 0, 0, 0);
      }
#pragma unroll
    for (int j = 0; j < 8; ++j)
#pragma unroll
      for (int r = 0; r < 4; ++r) s[j][r] *= 0.125f;

    // save raw scaled S to LDS (for weights output)
#pragma unroll
    for (int j = 0; j < 8; ++j)
#pragma unroll
      for (int r = 0; r < 4; ++r)
        Sr[(w * 16 + quad * 4 + r) * 136 + j * 16 + col] = f2bf(s[j][r]);

    // online softmax (no key mask: all 2048 keys valid)
#pragma unroll
    for (int r = 0; r < 4; ++r) {
      float tm = s[0][r];
#pragma unroll
      for (int j = 1; j < 8; ++j) tm = fmaxf(tm, s[j][r]);
#pragma unroll
      for (int o = 1; o <= 8; o <<= 1) tm = fmaxf(tm, __shfl_xor(tm, o));
      float mnew = fmaxf(mr[r], tm);
      float alpha = __expf(mr[r] - mnew);
      mr[r] = mnew;
      float ps = 0.f;
#pragma unroll
      for (int j = 0; j < 8; ++j) {
        float p = __expf(s[j][r] - mnew);
        s[j][r] = p;
        ps += p;
      }
#pragma unroll
      for (int o = 1; o <= 8; o <<= 1) ps += __shfl_xor(ps, o);
      lr[r] = lr[r] * alpha + ps;
#pragma unroll
      for (int n = 0; n < 4; ++n) O[n][r] *= alpha;
    }
#pragma unroll
    for (int j = 0; j < 8; ++j)
#pragma unroll
      for (int r = 0; r < 4; ++r)
        Pw[(quad * 4 + r) * 136 + j * 16 + col] = f2bf(s[j][r]);

#pragma unroll
    for (int kk = 0; kk < 4; ++kk) {
      s16x8 aP = *(const s16x8*)&Pw[col * 136 + kk * 32 + quad * 8];
#pragma unroll
      for (int n = 0; n < 4; ++n) {
        s16x8 bV = *(const s16x8*)&Vl[(n * 16 + col) * 136 + kk * 32 + quad * 8];
        O[n] = __builtin_amdgcn_mfma_f32_16x16x32_bf16(aP, bV, O[n], 0, 0, 0);
      }
    }
    __syncthreads();
    // coalesced raw-S dump: 64 rows x 128 cols
#pragma unroll
    for (int v = 0; v < 4; ++v) {
      int idx = v * 256 + t;
      int row = idx >> 4, c16 = idx & 15;
      *(uint4*)&S[((long)bh * SLQ + qt * 64 + row) * SLK + k0 + c16 * 8] =
          *(const uint4*)&Sr[row * 136 + c16 * 8];
    }
  }

#pragma unroll
  for (int r = 0; r < 4; ++r) {
    int qrow = qt * 64 + w * 16 + quad * 4 + r;
    long gq = (long)bh * SLQ + qrow;
#pragma unroll
    for (int n = 0; n < 4; ++n)
      Opart[(gq * 4 + kc) * 64 + n * 16 + col] = O[n][r];
    if (col == 0) mlc[gq * 4 + kc] = (float2){mr[r], lr[r]};
  }
}

// merge 4 chunk partials -> attn bf16 + final (M,L) stats
__global__ __launch_bounds__(256)
void cross_combine(const float* __restrict__ Opart, const float2* __restrict__ mlc,
                   u16* __restrict__ attn, float2* __restrict__ stats,
                   const int* __restrict__ qlen)
{
  int gr = blockIdx.x * 16 + (threadIdx.x >> 4);
  int bh = gr >> 10, q = gr & 1023;
  int b = bh >> 3, h = bh & 7;
  if (q >= qlen[b]) return;
  int d = (threadIdx.x & 15) * 4;
  float2 m0 = mlc[(long)gr * 4], m1 = mlc[(long)gr * 4 + 1];
  float2 m2 = mlc[(long)gr * 4 + 2], m3 = mlc[(long)gr * 4 + 3];
  float M = fmaxf(fmaxf(m0.x, m1.x), fmaxf(m2.x, m3.x));
  float w0 = __expf(m0.x - M), w1 = __expf(m1.x - M);
  float w2 = __expf(m2.x - M), w3 = __expf(m3.x - M);
  float L = m0.y * w0 + m1.y * w1 + m2.y * w2 + m3.y * w3;
  float4 o0 = *(const float4*)&Opart[((long)gr * 4 + 0) * 64 + d];
  float4 o1 = *(const float4*)&Opart[((long)gr * 4 + 1) * 64 + d];
  float4 o2 = *(const float4*)&Opart[((long)gr * 4 + 2) * 64 + d];
  float4 o3 = *(const float4*)&Opart[((long)gr * 4 + 3) * 64 + d];
  float inv = 1.0f / L;
  float ax = (o0.x * w0 + o1.x * w1 + o2.x * w2 + o3.x * w3) * inv;
  float ay = (o0.y * w0 + o1.y * w1 + o2.y * w2 + o3.y * w3) * inv;
  float az = (o0.z * w0 + o1.z * w1 + o2.z * w2 + o3.z * w3) * inv;
  float aw = (o0.w * w0 + o1.w * w1 + o2.w * w2 + o3.w * w3) * inv;
  unsigned int lo = (unsigned int)f2bf(ax) | ((unsigned int)f2bf(ay) << 16);
  unsigned int hi = (unsigned int)f2bf(az) | ((unsigned int)f2bf(aw) << 16);
  *(uint2*)&attn[((long)b * SLQ + q) * EE + h * HD + d] = (uint2){lo, hi};
  if ((threadIdx.x & 15) == 0) stats[gr] = (float2){M, L};
}

// weights output: mean over heads of exp(S - M)/L, f32
__global__ __launch_bounds__(256)
void wmean_final(const u16* __restrict__ S, const float2* __restrict__ stats,
                 float* __restrict__ outw, const int* __restrict__ qlen) {
  int row = blockIdx.x;               // b*1024 + q
  int b = row >> 10, q = row & 1023;
  int t = threadIdx.x, lane = t & 63, w = t >> 6;
  float* wr = outw + (long)row * SLK;
  if (q >= qlen[b]) {
    float4 z = {0.f, 0.f, 0.f, 0.f};
    *(float4*)(wr + t * 8) = z; *(float4*)(wr + t * 8 + 4) = z;
    return;
  }
  __shared__ float acc4[4][2048];
#pragma unroll
  for (int hh = 0; hh < 2; ++hh) {
    int h = 2 * w + hh;
    float2 st = stats[(long)(b * HH + h) * SLQ + q];
    float M = st.x, sc = 0.125f / st.y;
    const u16* p = S + ((long)((b * HH + h) * SLQ + q)) * SLK;
#pragma unroll
    for (int c = 0; c < 4; ++c) {
      s16x8 v = *(const s16x8*)(p + c * 512 + lane * 8);
      float x[8];
#pragma unroll
      for (int j = 0; j < 8; ++j) x[j] = __expf(bf2f((u16)v[j]) - M) * sc;
      float4 v0 = {x[0], x[1], x[2], x[3]};
      float4 v1 = {x[4], x[5], x[6], x[7]};
      if (hh == 0) {
        *(float4*)&acc4[w][c * 512 + lane * 8] = v0;
        *(float4*)&acc4[w][c * 512 + lane * 8 + 4] = v1;
      } else {
        float4 a0 = *(const float4*)&acc4[w][c * 512 + lane * 8];
        float4 a1 = *(const float4*)&acc4[w][c * 512 + lane * 8 + 4];
        a0.x += v0.x; a0.y += v0.y; a0.z += v0.z; a0.w += v0.w;
        a1.x += v1.x; a1.y += v1.y; a1.z += v1.z; a1.w += v1.w;
        *(float4*)&acc4[w][c * 512 + lane * 8] = a0;
        *(float4*)&acc4[w][c * 512 + lane * 8 + 4] = a1;
      }
    }
  }
  __syncthreads();
#pragma unroll
  for (int u = 0; u < 2; ++u) {
    int k = t * 8 + u * 4;
    float4 s0 = *(const float4*)&acc4[0][k];
    float4 s1 = *(const float4*)&acc4[1][k];
    float4 s2 = *(const float4*)&acc4[2][k];
    float4 s3 = *(const float4*)&acc4[3][k];
    float4 o = {s0.x + s1.x + s2.x + s3.x, s0.y + s1.y + s2.y + s3.y,
                s0.z + s1.z + s2.z + s3.z, s0.w + s1.w + s2.w + s3.w};
    *(float4*)(wr + k) = o;
  }
}

// ------------- self-attention: chunked flash (one K-chunk per block) --------
__global__ __launch_bounds__(256, 3)
void self_flash_chunk(const u16* __restrict__ Qc, const u16* __restrict__ Kc,
                      const u16* __restrict__ Vt, float* __restrict__ Opart,
                      float* __restrict__ ml, const int* __restrict__ qlen)
{
  const int qt = blockIdx.x;
  const int bh = blockIdx.y;
  const int ck = blockIdx.z;
  const int b = bh >> 3;
  const int kmax = qlen[b];
  const int k0 = ck * 128;
  if (qt * 64 >= kmax || k0 >= kmax) return;

  __shared__ __align__(16) u16 Kt[128 * 72];
  __shared__ __align__(16) u16 Vl[64 * 136];
  __shared__ __align__(16) u16 Pl[4 * 16 * 136];

  const int t = threadIdx.x, lane = t & 63, w = t >> 6;
  const int col = lane & 15, quad = lane >> 4;

  const u16* Qb = Qc + (long)bh * SLQ * HD;
  const u16* Kb = Kc + (long)bh * SLQ * HD;
  const u16* Vb = Vt + (long)bh * HD * SLQ;

  for (int c = t; c < 1024; c += 256) {
    int r = c >> 3, c8 = c & 7;
    *(uint4*)&Kt[r * 72 + c8 * 8] = *(const uint4*)(Kb + (long)(k0 + r) * HD + c8 * 8);
  }
  for (int c = t; c < 1024; c += 256) {
    int d = c >> 4, c16 = c & 15;
    *(uint4*)&Vl[d * 136 + c16 * 8] = *(const uint4*)(Vb + (long)d * SLQ + k0 + c16 * 8);
  }
  s16x8 aQ[2];
#pragma unroll
  for (int kk = 0; kk < 2; ++kk)
    aQ[kk] = *(const s16x8*)(Qb + (long)(qt * 64 + w * 16 + col) * HD + kk * 32 + quad * 8);
  __syncthreads();

  f32x4 s[8];
#pragma unroll
  for (int j = 0; j < 8; ++j) s[j] = (f32x4){0.f, 0.f, 0.f, 0.f};
#pragma unroll
  for (int j = 0; j < 8; ++j)
#pragma unroll
    for (int kk = 0; kk < 2; ++kk) {
      s16x8 bK = *(const s16x8*)&Kt[(j * 16 + col) * 72 + kk * 32 + quad * 8];
      s[j] = __builtin_amdgcn_mfma_f32_16x16x32_bf16(aQ[kk], bK, s[j], 0, 0, 0);
    }
#pragma unroll
  for (int j = 0; j < 8; ++j) {
    bool ok = (k0 + j * 16 + col) < kmax;
#pragma unroll
    for (int r = 0; r < 4; ++r)
      s[j][r] = ok ? s[j][r] * 0.125f : -1e30f;
  }
  float mr[4], lr[4];
#pragma unroll
  for (int r = 0; r < 4; ++r) {
    float tm = s[0][r];
#pragma unroll
    for (int j = 1; j < 8; ++j) tm = fmaxf(tm, s[j][r]);
#pragma unroll
    for (int o = 1; o <= 8; o <<= 1) tm = fmaxf(tm, __shfl_xor(tm, o));
    mr[r] = tm;
    float ps = 0.f;
#pragma unroll
    for (int j = 0; j < 8; ++j) {
      float p = __expf(s[j][r] - tm);
      s[j][r] = p;
      ps += p;
    }
#pragma unroll
    for (int o = 1; o <= 8; o <<= 1) ps += __shfl_xor(ps, o);
    lr[r] = ps;
  }
  u16* Pw = Pl + w * 16 * 136;
#pragma unroll
  for (int j = 0; j < 8; ++j)
#pragma unroll
    for (int r = 0; r < 4; ++r)
      Pw[(quad * 4 + r) * 136 + j * 16 + col] = f2bf(s[j][r]);

  f32x4 O[4];
#pragma unroll
  for (int n = 0; n < 4; ++n) O[n] = (f32x4){0.f, 0.f, 0.f, 0.f};
#pragma unroll
  for (int kk = 0; kk < 4; ++kk) {
    s16x8 aP = *(const s16x8*)&Pw[col * 136 + kk * 32 + quad * 8];
#pragma unroll
    for (int n = 0; n < 4; ++n) {
      s16x8 bV = *(const s16x8*)&Vl[(n * 16 + col) * 136 + kk * 32 + quad * 8];
      O[n] = __builtin_amdgcn_mfma_f32_16x16x32_bf16(aP, bV, O[n], 0, 0, 0);
    }
  }
#pragma unroll
  for (int r = 0; r < 4; ++r) {
    int q = qt * 64 + w * 16 + quad * 4 + r;
    long gq = (long)bh * SLQ + q;
#pragma unroll
    for (int n = 0; n < 4; ++n)
      Opart[(gq * 8 + ck) * 64 + n * 16 + col] = O[n][r];
    if (col == 0) {
      ml[(gq * 8 + ck) * 2] = mr[r];
      ml[(gq * 8 + ck) * 2 + 1] = lr[r];
    }
  }
}

__global__ __launch_bounds__(256)
void self_combine(const float* __restrict__ Opart, const float* __restrict__ ml,
                  u16* __restrict__ attn, const int* __restrict__ qlen)
{
  int gr = blockIdx.x * 16 + (threadIdx.x >> 4);
  int bh = gr >> 10, q = gr & 1023;
  int b = bh >> 3, h = bh & 7;
  int kmax = qlen[b];
  if (q >= kmax) return;
  int NC = (kmax + 127) >> 7;
  int d = (threadIdx.x & 15) * 4;
  long base = (long)gr * 8;
  float M = -1e30f;
  for (int c = 0; c < NC; ++c) M = fmaxf(M, ml[(base + c) * 2]);
  float L = 0.f;
  float ax = 0.f, ay = 0.f, az = 0.f, aw = 0.f;
  for (int c = 0; c < NC; ++c) {
    float wgt = __expf(ml[(base + c) * 2] - M);
    L += ml[(base + c) * 2 + 1] * wgt;
    float4 o = *(const float4*)&Opart[(base + c) * 64 + d];
    ax += o.x * wgt; ay += o.y * wgt; az += o.z * wgt; aw += o.w * wgt;
  }
  float inv = 1.0f / L;
  unsigned int lo = (unsigned int)f2bf(ax * inv) | ((unsigned int)f2bf(ay * inv) << 16);
  unsigned int hi = (unsigned int)f2bf(az * inv) | ((unsigned int)f2bf(aw * inv) << 16);
  *(uint2*)&attn[((long)b * SLQ + q) * EE + h * HD + d] = (uint2){lo, hi};
}

__global__ __launch_bounds__(256)
void cvt_kernel(const float* __restrict__ in, u16* __restrict__ out) {
  long base = ((long)blockIdx.x * 256 + threadIdx.x) * 8;
  float4 a = *(const float4*)&in[base];
  float4 b = *(const float4*)&in[base + 4];
  s16x8 o;
  o[0] = (short)f2bf(a.x); o[1] = (short)f2bf(a.y);
  o[2] = (short)f2bf(a.z); o[3] = (short)f2bf(a.w);
  o[4] = (short)f2bf(b.x); o[5] = (short)f2bf(b.y);
  o[6] = (short)f2bf(b.z); o[7] = (short)f2bf(b.w);
  *(s16x8*)&out[base] = o;
}

__global__ __launch_bounds__(256)
void wcvt_kernel(const float* s0, const float* s1, const float* s2,
                 const float* s3, const float* s4, const float* s5,
                 const float* s6, const float* s7, const float* s8,
                 u16* __restrict__ dst) {
  int mat = blockIdx.x >> 7, part = blockIdx.x & 127;
  const float* srcs[9] = {s0, s1, s2, s3, s4, s5, s6, s7, s8};
  const float* src = srcs[mat];
  long off = (long)part * 2048 + threadIdx.x * 8;
  float4 a = *(const float4*)&src[off];
  float4 b = *(const float4*)&src[off + 4];
  s16x8 o;
  o[0] = (short)f2bf(a.x); o[1] = (short)f2bf(a.y);
  o[2] = (short)f2bf(a.z); o[3] = (short)f2bf(a.w);
  o[4] = (short)f2bf(b.x); o[5] = (short)f2bf(b.y);
  o[6] = (short)f2bf(b.z); o[7] = (short)f2bf(b.w);
  *(s16x8*)&dst[(long)mat * EE * EE + off] = o;
}

__global__ __launch_bounds__(256)
void mask_q_kernel(const float* __restrict__ in, u16* __restrict__ out,
                   const int* __restrict__ qlen) {
  long base = ((long)blockIdx.x * 256 + threadIdx.x) * 8;
  int row = (int)(base >> 9);
  int b = row >> 10, q = row & 1023;
  s16x8 o = (s16x8){0, 0, 0, 0, 0, 0, 0, 0};
  if (q < qlen[b]) {
    float4 a = *(const float4*)&in[base];
    float4 c = *(const float4*)&in[base + 4];
    o[0] = (short)f2bf(a.x); o[1] = (short)f2bf(a.y);
    o[2] = (short)f2bf(a.z); o[3] = (short)f2bf(a.w);
    o[4] = (short)f2bf(c.x); o[5] = (short)f2bf(c.y);
    o[6] = (short)f2bf(c.z); o[7] = (short)f2bf(c.w);
  }
  *(s16x8*)&out[base] = o;
}

__device__ __forceinline__ float blockSum(float v, float* red4) {
#pragma unroll
  for (int o = 32; o; o >>= 1) v += __shfl_xor(v, o);
  if ((threadIdx.x & 63) == 0) red4[threadIdx.x >> 6] = v;
  __syncthreads();
  v = red4[0] + red4[1] + red4[2] + red4[3];
  __syncthreads();
  return v;
}

template<int OUTF32>
__global__ __launch_bounds__(256)
void silu_ln_kernel(const u16* __restrict__ x1, const u16* __restrict__ x2,
                    const float* __restrict__ g, const float* __restrict__ beta,
                    const int* __restrict__ qlen, void* __restrict__ outv, int mode) {
  int row = blockIdx.x;
  int b = row >> 10, q = row & 1023;
  int t = threadIdx.x;
  if (mode && q >= qlen[b]) {
    if (mode == 1) {
      if (OUTF32) {
        float* o = (float*)outv + (long)row * EE;
        o[2 * t] = 0.f; o[2 * t + 1] = 0.f;
      } else {
        u16* o = (u16*)outv + (long)row * EE;
        *(unsigned int*)&o[2 * t] = 0u;
      }
    }
    return;
  }
  __shared__ float red4[4];
  const u16* p1 = x1 + (long)row * EE;
  const u16* p2 = x2 + (long)row * EE;
  float a0 = bf2f(p1[2 * t]) + bf2f(p2[2 * t]);
  float a1 = bf2f(p1[2 * t + 1]) + bf2f(p2[2 * t + 1]);
  a0 = a0 / (1.f + __expf(-a0));
  a1 = a1 / (1.f + __expf(-a1));
  float mu = blockSum(a0 + a1, red4) * (1.f / 512.f);
  float d0 = a0 - mu, d1 = a1 - mu;
  float var = blockSum(d0 * d0 + d1 * d1, red4) * (1.f / 512.f);
  float rs = rsqrtf(var + 1e-5f);
  float r0 = d0 * rs * g[2 * t] + beta[2 * t];
  float r1 = d1 * rs * g[2 * t + 1] + beta[2 * t + 1];
  if (OUTF32) {
    float* o = (float*)outv + (long)row * EE;
    o[2 * t] = r0; o[2 * t + 1] = r1;
  } else {
    u16* o = (u16*)outv + (long)row * EE;
    o[2 * t] = f2bf(r0); o[2 * t + 1] = f2bf(r1);
  }
}

extern "C" void kernel_launch(void* const* d_in, const int* in_sizes, int n_in,
                              void* d_out, int out_size, void* d_ws, size_t ws_size,
                              hipStream_t stream) {
  const float* queries = (const float*)d_in[0];
  const float* keys    = (const float*)d_in[1];
  const int*   qlen    = (const int*)d_in[2];
  const float* cWq = (const float*)d_in[3],  *cbq = (const float*)d_in[4];
  const float* cWk = (const float*)d_in[5],  *cbk = (const float*)d_in[6];
  const float* cWv = (const float*)d_in[7],  *cbv = (const float*)d_in[8];
  const float* cWo = (const float*)d_in[9],  *cbo = (const float*)d_in[10];
  const float* sWq = (const float*)d_in[11], *sbq = (const float*)d_in[12];
  const float* sWk = (const float*)d_in[13], *sbk = (const float*)d_in[14];
  const float* sWv = (const float*)d_in[15], *sbv = (const float*)d_in[16];
  const float* sWo = (const float*)d_in[17], *sbo = (const float*)d_in[18];
  const float* Wf  = (const float*)d_in[19], *bfb = (const float*)d_in[20];
  const float* g_cross = (const float*)d_in[21], *b_cross = (const float*)d_in[22];
  const float* g_ffn   = (const float*)d_in[23], *b_ffn   = (const float*)d_in[24];
  const float* g_self  = (const float*)d_in[25], *b_self  = (const float*)d_in[26];

  float* out_q = (float*)d_out;
  float* out_w = out_q + (long)BB * SLQ * EE;

  u16* ws = (u16*)d_ws;
  u16* S     = ws;                               // 67,108,864 u16
  u16* Qc    = S   + (long)BB * HH * SLQ * SLK;
  u16* Kc    = Qc  + (long)BB * HH * SLQ * HD;
  u16* Vt    = Kc  + (long)BB * HH * SLK * HD;
  u16* q0    = Vt  + (long)BB * HH * SLK * HD;
  u16* keysb = q0  + (long)BB * SLQ * EE;
  u16* attn  = keysb + (long)BB * SLK * EE;
  u16* proj  = attn + (long)BB * SLQ * EE;
  u16* q1    = proj + (long)BB * SLQ * EE;
  u16* fbuf  = q1  + (long)BB * SLQ * EE;
  u16* q2    = fbuf + (long)BB * SLQ * EE;
  u16* Wb    = q2  + (long)BB * SLQ * EE;
  const long WSLOT = (long)EE * EE;
  float*  CpF  = (float*)(Wb + 9 * WSLOT);        // cross O partials: 32768*4*64 f32
  float2* mlc  = (float2*)(CpF + 8388608);        // 32768*4 float2
  float2* stat = (float2*)(mlc + 131072);         // 32768 float2

  // self-flash partials overlay the S region (S dead after wmean_final)
  float* OpS = (float*)S;
  float* mlS = (float*)(S + 33554432);

  u16* bWq = Wb + 0 * WSLOT; u16* bWk = Wb + 1 * WSLOT; u16* bWv = Wb + 2 * WSLOT;
  u16* bWo = Wb + 3 * WSLOT; u16* bsWq = Wb + 4 * WSLOT; u16* bsWk = Wb + 5 * WSLOT;
  u16* bsWv = Wb + 6 * WSLOT; u16* bsWo = Wb + 7 * WSLOT; u16* bWf = Wb + 8 * WSLOT;

  dim3 blk(256);
  const int MQ = BB * SLQ;   // 4096
  const int MK = BB * SLK;   // 8192

  mask_q_kernel<<<dim3((MQ * EE) / 2048), blk, 0, stream>>>(queries, q0, qlen);
  cvt_kernel<<<dim3((MK * EE) / 2048), blk, 0, stream>>>(keys, keysb);
  wcvt_kernel<<<dim3(9 * 128), blk, 0, stream>>>(cWq, cWk, cWv, cWo, sWq, sWk, sWv, sWo, Wf, Wb);

  // cross projections
  gemm_nt<64, 128, 1, 2><<<dim3(EE / 128, MQ / 64, 1), blk, 0, stream>>>(
      q0, bWq, cbq, Qc, MQ, EE, EE, EE, EE, 0, 0, 0, 0, 1.0f, SLQ, qlen);
  gemm_nt<128, 128, 1, 0><<<dim3(EE / 128, MK / 128, 1), blk, 0, stream>>>(
      keysb, bWk, cbk, Kc, MK, EE, EE, EE, EE, 0, 0, 0, 0, 1.0f, SLK, qlen);
  gemm_nt<128, 128, 2, 0><<<dim3(EE / 128, MK / 128, 1), blk, 0, stream>>>(
      keysb, bWv, cbv, Vt, MK, EE, EE, EE, EE, 0, 0, 0, 0, 1.0f, SLK, qlen);

  // fused cross attention: flash (writes raw S + O partials) -> combine -> wmean
  cross_flash_chunk<<<dim3(16, 32, 4), blk, 0, stream>>>(Qc, Kc, Vt, S, CpF, mlc, qlen);
  cross_combine<<<dim3(2048), blk, 0, stream>>>(CpF, mlc, attn, stat, qlen);
  wmean_final<<<dim3(BB * SLQ), blk, 0, stream>>>(S, stat, out_w, qlen);

  gemm_nt<64, 128, 0, 2><<<dim3(EE / 128, MQ / 64, 1), blk, 0, stream>>>(
      attn, bWo, cbo, proj, MQ, EE, EE, EE, EE, EE, 0, 0, 0, 1.0f, SLQ, qlen);

  silu_ln_kernel<0><<<dim3(MQ), blk, 0, stream>>>(proj, q0, g_cross, b_cross, qlen, q1, 2);

  gemm_nt<64, 128, 0, 2><<<dim3(EE / 128, MQ / 64, 1), blk, 0, stream>>>(
      q1, bWf, bfb, fbuf, MQ, EE, EE, EE, EE, EE, 0, 0, 0, 1.0f, SLQ, qlen);

  silu_ln_kernel<0><<<dim3(MQ), blk, 0, stream>>>(q1, fbuf, g_ffn, b_ffn, qlen, q2, 1);

  // self projections
  gemm_nt<64, 128, 1, 2><<<dim3(EE / 128, MQ / 64, 1), blk, 0, stream>>>(
      q2, bsWq, sbq, Qc, MQ, EE, EE, EE, EE, 0, 0, 0, 0, 1.0f, SLQ, qlen);
  gemm_nt<64, 128, 1, 2><<<dim3(EE / 128, MQ / 64, 1), blk, 0, stream>>>(
      q2, bsWk, sbk, Kc, MQ, EE, EE, EE, EE, 0, 0, 0, 0, 1.0f, SLQ, qlen);
  gemm_nt<64, 128, 2, 2><<<dim3(EE / 128, MQ / 64, 1), blk, 0, stream>>>(
      q2, bsWv, sbv, Vt, MQ, EE, EE, EE, EE, 0, 0, 0, 0, 1.0f, SLQ, qlen);

  // fused self attention (partials overlay S)
  self_flash_chunk<<<dim3(16, 32, 8), blk, 0, stream>>>(Qc, Kc, Vt, OpS, mlS, qlen);
  self_combine<<<dim3(2048), blk, 0, stream>>>(OpS, mlS, attn, qlen);

  gemm_nt<64, 128, 0, 2><<<dim3(EE / 128, MQ / 64, 1), blk, 0, stream>>>(
      attn, bsWo, sbo, proj, MQ, EE, EE, EE, EE, EE, 0, 0, 0, 1.0f, SLQ, qlen);

  silu_ln_kernel<1><<<dim3(MQ), blk, 0, stream>>>(q2, proj, g_self, b_self, qlen, out_q, 1);
}

// Round 7
// 349.511 us; speedup vs baseline: 1.1543x; 1.1543x over previous
//
#include <hip/hip_runtime.h>

#define BB 4
#define SLQ 1024
#define SLK 2048
#define EE 512
#define HH 8
#define HD 64

typedef unsigned short u16;
typedef __attribute__((ext_vector_type(8))) short s16x8;
typedef __attribute__((ext_vector_type(4))) float f32x4;

__device__ __forceinline__ float bf2f(u16 u) {
  union { unsigned int i; float f; } v; v.i = ((unsigned int)u) << 16; return v.f;
}
__device__ __forceinline__ u16 f2bf(float f) {
  union { float f; unsigned int i; } v; v.f = f;
  unsigned int i = v.i;
  return (u16)((i + 0x7fffu + ((i >> 16) & 1u)) >> 16);
}

__device__ __forceinline__ void async16(const u16* g, u16* l) {
  __builtin_amdgcn_global_load_lds(
      (const __attribute__((address_space(1))) unsigned int*)g,
      (__attribute__((address_space(3))) unsigned int*)l, 16, 0, 0);
}

// NT GEMM: C[m,n] = alpha * sum_k A[m,k]*B[n,k] + bias[n]   (A,B bf16; bias f32)
// MODE 0: C + z*sCz row-major, LDS-staged coalesced C write
// MODE 1: head-split [B,H,Lsub,64]
// MODE 2: head-split transposed [B,H,64,Lsub], LDS-staged coalesced write
// SKIPQ 0: none; 1: b=z>>3, skip tileM>=qlen[b]; 2: b=tileM>>10 (Lsub=1024)
template<int BM, int BN, int MODE, int SKIPQ>
__global__ __launch_bounds__(256, 2)
void gemm_nt(const u16* __restrict__ A, const u16* __restrict__ Bm,
             const float* __restrict__ bias, u16* __restrict__ C,
             int M, int N, int K, int lda, int ldb, int ldc,
             long sAz, long sBz, long sCz, float alpha, int Lsub,
             const int* __restrict__ qlen)
{
  constexpr int WTM = BM / 2, WTN = BN / 2;
  constexpr int MI = WTM / 16, NI = WTN / 16;

  const int z = blockIdx.z;
  const int tileM = blockIdx.y * BM;
  const int tileN = blockIdx.x * BN;

  if (SKIPQ == 1) { if (tileM >= qlen[z >> 3]) return; }
  if (SKIPQ == 2) { int b = tileM >> 10; if ((tileM & 1023) >= qlen[b]) return; }

  __shared__ __align__(16) u16 smem[(BM + BN) * 32];
  u16* ldsA = smem;
  u16* ldsB = smem + BM * 32;

  const int t = threadIdx.x;
  const int lane = t & 63;
  const int wave = t >> 6;
  const int waveM = wave >> 1;
  const int waveN = wave & 1;
  const int lm = lane & 15;
  const int kg = lane >> 4;

  const u16* Ab = A + (long)z * sAz + (long)tileM * lda;
  const u16* Bb = Bm + (long)z * sBz + (long)tileN * ldb;

  f32x4 acc[MI][NI];
#pragma unroll
  for (int i = 0; i < MI; ++i)
#pragma unroll
    for (int j = 0; j < NI; ++j) acc[i][j] = (f32x4){0.f, 0.f, 0.f, 0.f};

  for (int kt = 0; kt < K; kt += 32) {
    __syncthreads();
#pragma unroll
    for (int i = 0; i < (BM * 4) / 256; ++i) {
      int c = i * 256 + t;
      async16(Ab + (long)(c >> 2) * lda + kt + (c & 3) * 8, ldsA + (c - lane) * 8);
    }
#pragma unroll
    for (int i = 0; i < (BN * 4) / 256; ++i) {
      int c = i * 256 + t;
      async16(Bb + (long)(c >> 2) * ldb + kt + (c & 3) * 8, ldsB + (c - lane) * 8);
    }
    __syncthreads();

    s16x8 aF[MI], bF[NI];
#pragma unroll
    for (int i = 0; i < MI; ++i)
      aF[i] = *(const s16x8*)&ldsA[(waveM * WTM + i * 16 + lm) * 32 + kg * 8];
#pragma unroll
    for (int j = 0; j < NI; ++j)
      bF[j] = *(const s16x8*)&ldsB[(waveN * WTN + j * 16 + lm) * 32 + kg * 8];
#pragma unroll
    for (int i = 0; i < MI; ++i)
#pragma unroll
      for (int j = 0; j < NI; ++j)
        acc[i][j] = __builtin_amdgcn_mfma_f32_16x16x32_bf16(aF[i], bF[j], acc[i][j], 0, 0, 0);
  }

  if (MODE == 0) {
#pragma unroll
    for (int c = 0; c < BM / 32; ++c) {
      const int rlo = c * 32;
      __syncthreads();
#pragma unroll
      for (int i = 0; i < MI; ++i) {
        int mbase = waveM * WTM + i * 16;
        if (mbase >= rlo && mbase < rlo + 32) {
#pragma unroll
          for (int j = 0; j < NI; ++j) {
            int n = waveN * WTN + j * 16 + lm;
            float bv = bias ? bias[tileN + n] : 0.0f;
#pragma unroll
            for (int r = 0; r < 4; ++r) {
              int m = mbase + kg * 4 + r;
              smem[(m - rlo) * BN + n] = f2bf(acc[i][j][r] * alpha + bv);
            }
          }
        }
      }
      __syncthreads();
#pragma unroll
      for (int v = 0; v < (32 * BN) / (256 * 8); ++v) {
        int idx = v * 256 + t;
        int row = idx / (BN / 8), col8 = idx % (BN / 8);
        *(uint4*)&C[(long)z * sCz + (long)(tileM + rlo + row) * ldc + tileN + col8 * 8] =
            *(const uint4*)&smem[row * BN + col8 * 8];
      }
    }
  } else if (MODE == 2) {
    constexpr int PAD = BM + 8;
    const int bb = tileM / Lsub;
    const int l0 = tileM - bb * Lsub;
#pragma unroll
    for (int c = 0; c < BN / 32; ++c) {
      __syncthreads();
#pragma unroll
      for (int j = 0; j < NI; ++j) {
        int nloc = waveN * WTN + j * 16 + lm;
        if (nloc >= c * 32 && nloc < c * 32 + 32) {
          int nl = nloc - c * 32;
          float bv = bias ? bias[tileN + nloc] : 0.0f;
#pragma unroll
          for (int i = 0; i < MI; ++i)
#pragma unroll
            for (int r = 0; r < 4; ++r) {
              int mm = waveM * WTM + i * 16 + kg * 4 + r;
              smem[nl * PAD + mm] = f2bf(acc[i][j][r] * alpha + bv);
            }
        }
      }
      __syncthreads();
#pragma unroll
      for (int v = 0; v < (32 * BM) / (256 * 8); ++v) {
        int idx = v * 256 + t;
        int nl = idx / (BM / 8), m8 = idx % (BM / 8);
        int n = tileN + c * 32 + nl;
        int h = n >> 6, d = n & 63;
        *(uint4*)&C[((long)(bb * HH + h) * HD + d) * Lsub + l0 + m8 * 8] =
            *(const uint4*)&smem[nl * PAD + m8 * 8];
      }
    }
  } else {
#pragma unroll
    for (int j = 0; j < NI; ++j) {
      int n = tileN + waveN * WTN + j * 16 + lm;
      float bv = bias ? bias[n] : 0.0f;
#pragma unroll
      for (int i = 0; i < MI; ++i) {
#pragma unroll
        for (int r = 0; r < 4; ++r) {
          int m = tileM + waveM * WTM + i * 16 + kg * 4 + r;
          float v = acc[i][j][r] * alpha + bv;
          int b = m / Lsub, l = m - b * Lsub;
          int h = n >> 6, d = n & 63;
          C[(((long)(b * HH + h) * Lsub + l) << 6) + d] = f2bf(v);
        }
      }
    }
  }
}

// cross softmax stats + head-mean weights (read-only over S)
__global__ __launch_bounds__(256)
void softmax_stats_wmean(const u16* __restrict__ S, float* __restrict__ outw,
                         float2* __restrict__ stats, const int* __restrict__ qlen) {
  int row = blockIdx.x;
  int b = row >> 10, q = row & 1023;
  int t = threadIdx.x, lane = t & 63, w = t >> 6;
  float* wr = outw + (long)row * SLK;
  if (q >= qlen[b]) {
    float4 z = {0.f, 0.f, 0.f, 0.f};
    *(float4*)(wr + t * 8) = z; *(float4*)(wr + t * 8 + 4) = z;
    return;
  }
  __shared__ float acc4[4][2048];
#pragma unroll
  for (int hh = 0; hh < 2; ++hh) {
    int h = 2 * w + hh;
    const u16* p = S + ((long)((b * HH + h) * SLQ + q)) * SLK;
    float x[4][8];
    float m = -1e30f;
#pragma unroll
    for (int c = 0; c < 4; ++c) {
      s16x8 v = *(const s16x8*)(p + c * 512 + lane * 8);
#pragma unroll
      for (int j = 0; j < 8; ++j) { x[c][j] = bf2f((u16)v[j]); m = fmaxf(m, x[c][j]); }
    }
#pragma unroll
    for (int o = 1; o <= 32; o <<= 1) m = fmaxf(m, __shfl_xor(m, o));
    float s = 0.f;
#pragma unroll
    for (int c = 0; c < 4; ++c)
#pragma unroll
      for (int j = 0; j < 8; ++j) { x[c][j] = __expf(x[c][j] - m); s += x[c][j]; }
#pragma unroll
    for (int o = 1; o <= 32; o <<= 1) s += __shfl_xor(s, o);
    if (lane == 0) stats[(long)(b * HH + h) * SLQ + q] = (float2){m, s};
    float sc = 0.125f / s;
#pragma unroll
    for (int c = 0; c < 4; ++c) {
      float4 v0 = {x[c][0] * sc, x[c][1] * sc, x[c][2] * sc, x[c][3] * sc};
      float4 v1 = {x[c][4] * sc, x[c][5] * sc, x[c][6] * sc, x[c][7] * sc};
      if (hh == 0) {
        *(float4*)&acc4[w][c * 512 + lane * 8] = v0;
        *(float4*)&acc4[w][c * 512 + lane * 8 + 4] = v1;
      } else {
        float4 a0 = *(const float4*)&acc4[w][c * 512 + lane * 8];
        float4 a1 = *(const float4*)&acc4[w][c * 512 + lane * 8 + 4];
        a0.x += v0.x; a0.y += v0.y; a0.z += v0.z; a0.w += v0.w;
        a1.x += v1.x; a1.y += v1.y; a1.z += v1.z; a1.w += v1.w;
        *(float4*)&acc4[w][c * 512 + lane * 8] = a0;
        *(float4*)&acc4[w][c * 512 + lane * 8 + 4] = a1;
      }
    }
  }
  __syncthreads();
#pragma unroll
  for (int u = 0; u < 2; ++u) {
    int k = t * 8 + u * 4;
    float4 s0 = *(const float4*)&acc4[0][k];
    float4 s1 = *(const float4*)&acc4[1][k];
    float4 s2 = *(const float4*)&acc4[2][k];
    float4 s3 = *(const float4*)&acc4[3][k];
    float4 o = {s0.x + s1.x + s2.x + s3.x, s0.y + s1.y + s2.y + s3.y,
                s0.z + s1.z + s2.z + s3.z, s0.w + s1.w + s2.w + s3.w};
    *(float4*)(wr + k) = o;
  }
}

// cross PV: direct-global S reads (A-fragment layout), LDS only for V
__global__ __launch_bounds__(256, 2)
void pv_cross(const u16* __restrict__ S, const u16* __restrict__ Vt,
              const float2* __restrict__ stats, float* __restrict__ Opart,
              const int* __restrict__ qlen)
{
  const int qt = blockIdx.x;           // 16 q-tiles of 64
  const int bh = blockIdx.y;           // 32
  const int kc = blockIdx.z;           // 4 chunks of 512 keys
  const int b = bh >> 3;
  if (qt * 64 >= qlen[b]) return;

  __shared__ __align__(16) u16 Vl[64 * 136];   // [d][128k] pad 136

  const int t = threadIdx.x, lane = t & 63, w = t >> 6;
  const int lm = lane & 15, quad = lane >> 4;

  const int qrow = qt * 64 + w * 16 + lm;
  const u16* Sb = S + ((long)bh * SLQ + qrow) * SLK;
  const u16* Vb = Vt + (long)bh * HD * SLK;
  const float mrow = stats[(long)bh * SLQ + qrow].x;

  f32x4 O[4];
#pragma unroll
  for (int n = 0; n < 4; ++n) O[n] = (f32x4){0.f, 0.f, 0.f, 0.f};

  for (int ks = 0; ks < 4; ++ks) {
    const int k0 = kc * 512 + ks * 128;
    __syncthreads();
    for (int c = t; c < 1024; c += 256) {
      int d = c >> 4, c16 = c & 15;
      *(uint4*)&Vl[d * 136 + c16 * 8] = *(const uint4*)(Vb + (long)d * SLK + k0 + c16 * 8);
    }
    __syncthreads();
#pragma unroll
    for (int kk = 0; kk < 4; ++kk) {
      s16x8 raw = *(const s16x8*)(Sb + k0 + kk * 32 + quad * 8);
      s16x8 aP;
#pragma unroll
      for (int j = 0; j < 8; ++j)
        aP[j] = (short)f2bf(__expf(bf2f((u16)raw[j]) - mrow));
#pragma unroll
      for (int n = 0; n < 4; ++n) {
        s16x8 bV = *(const s16x8*)&Vl[(n * 16 + lm) * 136 + kk * 32 + quad * 8];
        O[n] = __builtin_amdgcn_mfma_f32_16x16x32_bf16(aP, bV, O[n], 0, 0, 0);
      }
    }
  }

#pragma unroll
  for (int r = 0; r < 4; ++r) {
    int qr2 = qt * 64 + w * 16 + quad * 4 + r;
#pragma unroll
    for (int n = 0; n < 4; ++n)
      Opart[(((long)bh * SLQ + qr2) * 4 + kc) * 64 + n * 16 + lm] = O[n][r];
  }
}

// sum 4 split-K f32 partials, apply 1/l -> attn bf16
__global__ __launch_bounds__(256)
void pv_combine_cross(const float* __restrict__ Opart, const float2* __restrict__ stats,
                      u16* __restrict__ attn, const int* __restrict__ qlen)
{
  int gr = blockIdx.x * 16 + (threadIdx.x >> 4);
  int bh = gr >> 10, q = gr & 1023;
  int b = bh >> 3, h = bh & 7;
  if (q >= qlen[b]) return;
  int d = (threadIdx.x & 15) * 4;
  float ax = 0.f, ay = 0.f, az = 0.f, aw = 0.f;
#pragma unroll
  for (int c = 0; c < 4; ++c) {
    float4 o = *(const float4*)&Opart[((long)gr * 4 + c) * 64 + d];
    ax += o.x; ay += o.y; az += o.z; aw += o.w;
  }
  float inv = 1.0f / stats[gr].y;
  unsigned int lo = (unsigned int)f2bf(ax * inv) | ((unsigned int)f2bf(ay * inv) << 16);
  unsigned int hi = (unsigned int)f2bf(az * inv) | ((unsigned int)f2bf(aw * inv) << 16);
  *(uint2*)&attn[((long)b * SLQ + q) * EE + h * HD + d] = (uint2){lo, hi};
}

// ------------- self-attention: chunked flash (one K-chunk per block) --------
__global__ __launch_bounds__(256, 3)
void self_flash_chunk(const u16* __restrict__ Qc, const u16* __restrict__ Kc,
                      const u16* __restrict__ Vt, float* __restrict__ Opart,
                      float* __restrict__ ml, const int* __restrict__ qlen)
{
  const int qt = blockIdx.x;
  const int bh = blockIdx.y;
  const int ck = blockIdx.z;
  const int b = bh >> 3;
  const int kmax = qlen[b];
  const int k0 = ck * 128;
  if (qt * 64 >= kmax || k0 >= kmax) return;

  __shared__ __align__(16) u16 Kt[128 * 72];
  __shared__ __align__(16) u16 Vl[64 * 136];
  __shared__ __align__(16) u16 Pl[4 * 16 * 136];

  const int t = threadIdx.x, lane = t & 63, w = t >> 6;
  const int col = lane & 15, quad = lane >> 4;

  const u16* Qb = Qc + (long)bh * SLQ * HD;
  const u16* Kb = Kc + (long)bh * SLQ * HD;
  const u16* Vb = Vt + (long)bh * HD * SLQ;

  for (int c = t; c < 1024; c += 256) {
    int r = c >> 3, c8 = c & 7;
    *(uint4*)&Kt[r * 72 + c8 * 8] = *(const uint4*)(Kb + (long)(k0 + r) * HD + c8 * 8);
  }
  for (int c = t; c < 1024; c += 256) {
    int d = c >> 4, c16 = c & 15;
    *(uint4*)&Vl[d * 136 + c16 * 8] = *(const uint4*)(Vb + (long)d * SLQ + k0 + c16 * 8);
  }
  s16x8 aQ[2];
#pragma unroll
  for (int kk = 0; kk < 2; ++kk)
    aQ[kk] = *(const s16x8*)(Qb + (long)(qt * 64 + w * 16 + col) * HD + kk * 32 + quad * 8);
  __syncthreads();

  f32x4 s[8];
#pragma unroll
  for (int j = 0; j < 8; ++j) s[j] = (f32x4){0.f, 0.f, 0.f, 0.f};
#pragma unroll
  for (int j = 0; j < 8; ++j)
#pragma unroll
    for (int kk = 0; kk < 2; ++kk) {
      s16x8 bK = *(const s16x8*)&Kt[(j * 16 + col) * 72 + kk * 32 + quad * 8];
      s[j] = __builtin_amdgcn_mfma_f32_16x16x32_bf16(aQ[kk], bK, s[j], 0, 0, 0);
    }
#pragma unroll
  for (int j = 0; j < 8; ++j) {
    bool ok = (k0 + j * 16 + col) < kmax;
#pragma unroll
    for (int r = 0; r < 4; ++r)
      s[j][r] = ok ? s[j][r] * 0.125f : -1e30f;
  }
  float mr[4], lr[4];
#pragma unroll
  for (int r = 0; r < 4; ++r) {
    float tm = s[0][r];
#pragma unroll
    for (int j = 1; j < 8; ++j) tm = fmaxf(tm, s[j][r]);
#pragma unroll
    for (int o = 1; o <= 8; o <<= 1) tm = fmaxf(tm, __shfl_xor(tm, o));
    mr[r] = tm;
    float ps = 0.f;
#pragma unroll
    for (int j = 0; j < 8; ++j) {
      float p = __expf(s[j][r] - tm);
      s[j][r] = p;
      ps += p;
    }
#pragma unroll
    for (int o = 1; o <= 8; o <<= 1) ps += __shfl_xor(ps, o);
    lr[r] = ps;
  }
  u16* Pw = Pl + w * 16 * 136;
#pragma unroll
  for (int j = 0; j < 8; ++j)
#pragma unroll
    for (int r = 0; r < 4; ++r)
      Pw[(quad * 4 + r) * 136 + j * 16 + col] = f2bf(s[j][r]);

  f32x4 O[4];
#pragma unroll
  for (int n = 0; n < 4; ++n) O[n] = (f32x4){0.f, 0.f, 0.f, 0.f};
#pragma unroll
  for (int kk = 0; kk < 4; ++kk) {
    s16x8 aP = *(const s16x8*)&Pw[col * 136 + kk * 32 + quad * 8];
#pragma unroll
    for (int n = 0; n < 4; ++n) {
      s16x8 bV = *(const s16x8*)&Vl[(n * 16 + col) * 136 + kk * 32 + quad * 8];
      O[n] = __builtin_amdgcn_mfma_f32_16x16x32_bf16(aP, bV, O[n], 0, 0, 0);
    }
  }
#pragma unroll
  for (int r = 0; r < 4; ++r) {
    int q = qt * 64 + w * 16 + quad * 4 + r;
    long gq = (long)bh * SLQ + q;
#pragma unroll
    for (int n = 0; n < 4; ++n)
      Opart[(gq * 8 + ck) * 64 + n * 16 + col] = O[n][r];
    if (col == 0) {
      ml[(gq * 8 + ck) * 2] = mr[r];
      ml[(gq * 8 + ck) * 2 + 1] = lr[r];
    }
  }
}

__global__ __launch_bounds__(256)
void self_combine(const float* __restrict__ Opart, const float* __restrict__ ml,
                  u16* __restrict__ attn, const int* __restrict__ qlen)
{
  int gr = blockIdx.x * 16 + (threadIdx.x >> 4);
  int bh = gr >> 10, q = gr & 1023;
  int b = bh >> 3, h = bh & 7;
  int kmax = qlen[b];
  if (q >= kmax) return;
  int NC = (kmax + 127) >> 7;
  int d = (threadIdx.x & 15) * 4;
  long base = (long)gr * 8;
  float M = -1e30f;
  for (int c = 0; c < NC; ++c) M = fmaxf(M, ml[(base + c) * 2]);
  float L = 0.f;
  float ax = 0.f, ay = 0.f, az = 0.f, aw = 0.f;
  for (int c = 0; c < NC; ++c) {
    float wgt = __expf(ml[(base + c) * 2] - M);
    L += ml[(base + c) * 2 + 1] * wgt;
    float4 o = *(const float4*)&Opart[(base + c) * 64 + d];
    ax += o.x * wgt; ay += o.y * wgt; az += o.z * wgt; aw += o.w * wgt;
  }
  float inv = 1.0f / L;
  unsigned int lo = (unsigned int)f2bf(ax * inv) | ((unsigned int)f2bf(ay * inv) << 16);
  unsigned int hi = (unsigned int)f2bf(az * inv) | ((unsigned int)f2bf(aw * inv) << 16);
  *(uint2*)&attn[((long)b * SLQ + q) * EE + h * HD + d] = (uint2){lo, hi};
}

// fused input conversion: masked queries + keys + 9 weight matrices
__global__ __launch_bounds__(256)
void cvt_all(const float* __restrict__ queries, const float* __restrict__ keys,
             const int* __restrict__ qlen,
             const float* w0, const float* w1, const float* w2, const float* w3,
             const float* w4, const float* w5, const float* w6, const float* w7,
             const float* w8,
             u16* __restrict__ q0, u16* __restrict__ keysb, u16* __restrict__ Wb) {
  int blk = blockIdx.x;
  int t = threadIdx.x;
  const float* src;
  u16* dst;
  long off;
  bool mask = false;
  int b = 0, q = 0;
  if (blk < 1024) {                    // queries: 4096*512
    off = (long)blk * 2048 + t * 8;
    int row = (int)(off >> 9);
    b = row >> 10; q = row & 1023;
    mask = true;
    src = queries; dst = q0;
  } else if (blk < 3072) {             // keys: 8192*512
    off = (long)(blk - 1024) * 2048 + t * 8;
    src = keys; dst = keysb;
  } else {                             // weights
    int mat = (blk - 3072) >> 7, part = (blk - 3072) & 127;
    const float* srcs[9] = {w0, w1, w2, w3, w4, w5, w6, w7, w8};
    src = srcs[mat];
    off = (long)part * 2048 + t * 8;
    dst = Wb + (long)mat * EE * EE;
  }
  s16x8 o = (s16x8){0, 0, 0, 0, 0, 0, 0, 0};
  if (!mask || q < qlen[b]) {
    float4 a = *(const float4*)&src[off];
    float4 c = *(const float4*)&src[off + 4];
    o[0] = (short)f2bf(a.x); o[1] = (short)f2bf(a.y);
    o[2] = (short)f2bf(a.z); o[3] = (short)f2bf(a.w);
    o[4] = (short)f2bf(c.x); o[5] = (short)f2bf(c.y);
    o[6] = (short)f2bf(c.z); o[7] = (short)f2bf(c.w);
  }
  *(s16x8*)&dst[off] = o;
}

__device__ __forceinline__ float blockSum(float v, float* red4) {
#pragma unroll
  for (int o = 32; o; o >>= 1) v += __shfl_xor(v, o);
  if ((threadIdx.x & 63) == 0) red4[threadIdx.x >> 6] = v;
  __syncthreads();
  v = red4[0] + red4[1] + red4[2] + red4[3];
  __syncthreads();
  return v;
}

template<int OUTF32>
__global__ __launch_bounds__(256)
void silu_ln_kernel(const u16* __restrict__ x1, const u16* __restrict__ x2,
                    const float* __restrict__ g, const float* __restrict__ beta,
                    const int* __restrict__ qlen, void* __restrict__ outv, int mode) {
  int row = blockIdx.x;
  int b = row >> 10, q = row & 1023;
  int t = threadIdx.x;
  if (mode && q >= qlen[b]) {
    if (mode == 1) {
      if (OUTF32) {
        float* o = (float*)outv + (long)row * EE;
        o[2 * t] = 0.f; o[2 * t + 1] = 0.f;
      } else {
        u16* o = (u16*)outv + (long)row * EE;
        *(unsigned int*)&o[2 * t] = 0u;
      }
    }
    return;
  }
  __shared__ float red4[4];
  const u16* p1 = x1 + (long)row * EE;
  const u16* p2 = x2 + (long)row * EE;
  float a0 = bf2f(p1[2 * t]) + bf2f(p2[2 * t]);
  float a1 = bf2f(p1[2 * t + 1]) + bf2f(p2[2 * t + 1]);
  a0 = a0 / (1.f + __expf(-a0));
  a1 = a1 / (1.f + __expf(-a1));
  float mu = blockSum(a0 + a1, red4) * (1.f / 512.f);
  float d0 = a0 - mu, d1 = a1 - mu;
  float var = blockSum(d0 * d0 + d1 * d1, red4) * (1.f / 512.f);
  float rs = rsqrtf(var + 1e-5f);
  float r0 = d0 * rs * g[2 * t] + beta[2 * t];
  float r1 = d1 * rs * g[2 * t + 1] + beta[2 * t + 1];
  if (OUTF32) {
    float* o = (float*)outv + (long)row * EE;
    o[2 * t] = r0; o[2 * t + 1] = r1;
  } else {
    u16* o = (u16*)outv + (long)row * EE;
    o[2 * t] = f2bf(r0); o[2 * t + 1] = f2bf(r1);
  }
}

extern "C" void kernel_launch(void* const* d_in, const int* in_sizes, int n_in,
                              void* d_out, int out_size, void* d_ws, size_t ws_size,
                              hipStream_t stream) {
  const float* queries = (const float*)d_in[0];
  const float* keys    = (const float*)d_in[1];
  const int*   qlen    = (const int*)d_in[2];
  const float* cWq = (const float*)d_in[3],  *cbq = (const float*)d_in[4];
  const float* cWk = (const float*)d_in[5],  *cbk = (const float*)d_in[6];
  const float* cWv = (const float*)d_in[7],  *cbv = (const float*)d_in[8];
  const float* cWo = (const float*)d_in[9],  *cbo = (const float*)d_in[10];
  const float* sWq = (const float*)d_in[11], *sbq = (const float*)d_in[12];
  const float* sWk = (const float*)d_in[13], *sbk = (const float*)d_in[14];
  const float* sWv = (const float*)d_in[15], *sbv = (const float*)d_in[16];
  const float* sWo = (const float*)d_in[17], *sbo = (const float*)d_in[18];
  const float* Wf  = (const float*)d_in[19], *bfb = (const float*)d_in[20];
  const float* g_cross = (const float*)d_in[21], *b_cross = (const float*)d_in[22];
  const float* g_ffn   = (const float*)d_in[23], *b_ffn   = (const float*)d_in[24];
  const float* g_self  = (const float*)d_in[25], *b_self  = (const float*)d_in[26];

  float* out_q = (float*)d_out;
  float* out_w = out_q + (long)BB * SLQ * EE;

  u16* ws = (u16*)d_ws;
  u16* S     = ws;                               // 67,108,864 u16
  u16* Qc    = S   + (long)BB * HH * SLQ * SLK;
  u16* Kc    = Qc  + (long)BB * HH * SLQ * HD;
  u16* Vt    = Kc  + (long)BB * HH * SLK * HD;
  u16* q0    = Vt  + (long)BB * HH * SLK * HD;
  u16* keysb = q0  + (long)BB * SLQ * EE;
  u16* attn  = keysb + (long)BB * SLK * EE;
  u16* proj  = attn + (long)BB * SLQ * EE;
  u16* q1    = proj + (long)BB * SLQ * EE;
  u16* fbuf  = q1  + (long)BB * SLQ * EE;
  u16* q2    = fbuf + (long)BB * SLQ * EE;
  u16* Wb    = q2  + (long)BB * SLQ * EE;
  const long WSLOT = (long)EE * EE;
  float*  CpF  = (float*)(Wb + 9 * WSLOT);        // cross O partials: 32768*4*64 f32
  float2* stat = (float2*)(CpF + 8388608);        // 32768 float2

  // self-flash partials overlay the S region (S dead after pv_cross)
  float* OpS = (float*)S;
  float* mlS = (float*)(S + 33554432);

  u16* bWq = Wb + 0 * WSLOT; u16* bWk = Wb + 1 * WSLOT; u16* bWv = Wb + 2 * WSLOT;
  u16* bWo = Wb + 3 * WSLOT; u16* bsWq = Wb + 4 * WSLOT; u16* bsWk = Wb + 5 * WSLOT;
  u16* bsWv = Wb + 6 * WSLOT; u16* bsWo = Wb + 7 * WSLOT; u16* bWf = Wb + 8 * WSLOT;

  dim3 blk(256);
  const int MQ = BB * SLQ;   // 4096
  const int MK = BB * SLK;   // 8192

  cvt_all<<<dim3(3072 + 9 * 128), blk, 0, stream>>>(
      queries, keys, qlen, cWq, cWk, cWv, cWo, sWq, sWk, sWv, sWo, Wf, q0, keysb, Wb);

  // cross projections (64x64 tiles for occupancy)
  gemm_nt<64, 64, 1, 2><<<dim3(EE / 64, MQ / 64, 1), blk, 0, stream>>>(
      q0, bWq, cbq, Qc, MQ, EE, EE, EE, EE, 0, 0, 0, 0, 1.0f, SLQ, qlen);
  gemm_nt<64, 64, 1, 0><<<dim3(EE / 64, MK / 64, 1), blk, 0, stream>>>(
      keysb, bWk, cbk, Kc, MK, EE, EE, EE, EE, 0, 0, 0, 0, 1.0f, SLK, qlen);
  gemm_nt<64, 64, 2, 0><<<dim3(EE / 64, MK / 64, 1), blk, 0, stream>>>(
      keysb, bWv, cbv, Vt, MK, EE, EE, EE, EE, 0, 0, 0, 0, 1.0f, SLK, qlen);

  // S = Q K^T * 1/8  (coalesced staged C write, skip invalid q tiles)
  gemm_nt<128, 128, 0, 1><<<dim3(SLK / 128, SLQ / 128, BB * HH), blk, 0, stream>>>(
      Qc, Kc, nullptr, S, SLQ, SLK, HD, HD, HD, SLK,
      (long)SLQ * HD, (long)SLK * HD, (long)SLQ * SLK, 0.125f, 0, qlen);

  softmax_stats_wmean<<<dim3(BB * SLQ), blk, 0, stream>>>(S, out_w, stat, qlen);

  pv_cross<<<dim3(16, 32, 4), blk, 0, stream>>>(S, Vt, stat, CpF, qlen);
  pv_combine_cross<<<dim3(2048), blk, 0, stream>>>(CpF, stat, attn, qlen);

  gemm_nt<64, 64, 0, 2><<<dim3(EE / 64, MQ / 64, 1), blk, 0, stream>>>(
      attn, bWo, cbo, proj, MQ, EE, EE, EE, EE, EE, 0, 0, 0, 1.0f, SLQ, qlen);

  silu_ln_kernel<0><<<dim3(MQ), blk, 0, stream>>>(proj, q0, g_cross, b_cross, qlen, q1, 2);

  gemm_nt<64, 64, 0, 2><<<dim3(EE / 64, MQ / 64, 1), blk, 0, stream>>>(
      q1, bWf, bfb, fbuf, MQ, EE, EE, EE, EE, EE, 0, 0, 0, 1.0f, SLQ, qlen);

  silu_ln_kernel<0><<<dim3(MQ), blk, 0, stream>>>(q1, fbuf, g_ffn, b_ffn, qlen, q2, 1);

  // self projections
  gemm_nt<64, 64, 1, 2><<<dim3(EE / 64, MQ / 64, 1), blk, 0, stream>>>(
      q2, bsWq, sbq, Qc, MQ, EE, EE, EE, EE, 0, 0, 0, 0, 1.0f, SLQ, qlen);
  gemm_nt<64, 64, 1, 2><<<dim3(EE / 64, MQ / 64, 1), blk, 0, stream>>>(
      q2, bsWk, sbk, Kc, MQ, EE, EE, EE, EE, 0, 0, 0, 0, 1.0f, SLQ, qlen);
  gemm_nt<64, 64, 2, 2><<<dim3(EE / 64, MQ / 64, 1), blk, 0, stream>>>(
      q2, bsWv, sbv, Vt, MQ, EE, EE, EE, EE, 0, 0, 0, 0, 1.0f, SLQ, qlen);

  // fused self attention (partials overlay S)
  self_flash_chunk<<<dim3(16, 32, 8), blk, 0, stream>>>(Qc, Kc, Vt, OpS, mlS, qlen);
  self_combine<<<dim3(2048), blk, 0, stream>>>(OpS, mlS, attn, qlen);

  gemm_nt<64, 64, 0, 2><<<dim3(EE / 64, MQ / 64, 1), blk, 0, stream>>>(
      attn, bsWo, sbo, proj, MQ, EE, EE, EE, EE, EE, 0, 0, 0, 1.0f, SLQ, qlen);

  silu_ln_kernel<1><<<dim3(MQ), blk, 0, stream>>>(q2, proj, g_self, b_self, qlen, out_q, 1);
}

// Round 8
// 320.369 us; speedup vs baseline: 1.2593x; 1.0910x over previous
//
#include <hip/hip_runtime.h>

#define BB 4
#define SLQ 1024
#define SLK 2048
#define EE 512
#define HH 8
#define HD 64

typedef unsigned short u16;
typedef __attribute__((ext_vector_type(8))) short s16x8;
typedef __attribute__((ext_vector_type(4))) float f32x4;

__device__ __forceinline__ float bf2f(u16 u) {
  union { unsigned int i; float f; } v; v.i = ((unsigned int)u) << 16; return v.f;
}
__device__ __forceinline__ u16 f2bf(float f) {
  union { float f; unsigned int i; } v; v.f = f;
  unsigned int i = v.i;
  return (u16)((i + 0x7fffu + ((i >> 16) & 1u)) >> 16);
}

__device__ __forceinline__ void async16(const u16* g, u16* l) {
  __builtin_amdgcn_global_load_lds(
      (const __attribute__((address_space(1))) unsigned int*)g,
      (__attribute__((address_space(3))) unsigned int*)l, 16, 0, 0);
}

// NT GEMM: C[m,n] = alpha*sum_k A[m,k]*B[n,k] + bias[n]
// MODE 0: row-major, per-wave barrier-free staged write
// MODE 1: head-split [B,H,Lsub,64] direct scatter
// SKIPQ 0: none; 1: b=z>>3, skip tileM>=qlen[b]; 2: b=tileM>>10 (Lsub=1024)
template<int BM, int BN, int MODE, int SKIPQ>
__global__ __launch_bounds__(256, 2)
void gemm_nt(const u16* __restrict__ A, const u16* __restrict__ Bm,
             const float* __restrict__ bias, u16* __restrict__ C,
             int M, int N, int K, int lda, int ldb, int ldc,
             long sAz, long sBz, long sCz, float alpha, int Lsub,
             const int* __restrict__ qlen)
{
  constexpr int WTM = BM / 2, WTN = BN / 2;
  constexpr int MI = WTM / 16, NI = WTN / 16;
  constexpr int EPAD = WTN + 8;
  constexpr int SM1 = (BM + BN) * 32;
  constexpr int SM2 = (MODE == 0) ? 4 * WTM * EPAD : 0;
  constexpr int SM = (SM1 > SM2) ? SM1 : SM2;

  const int z = blockIdx.z;
  const int tileM = blockIdx.y * BM;
  const int tileN = blockIdx.x * BN;

  if (SKIPQ == 1) { if (tileM >= qlen[z >> 3]) return; }
  if (SKIPQ == 2) { int b = tileM >> 10; if ((tileM & 1023) >= qlen[b]) return; }

  __shared__ __align__(16) u16 smem[SM];
  u16* ldsA = smem;
  u16* ldsB = smem + BM * 32;

  const int t = threadIdx.x;
  const int lane = t & 63;
  const int wave = t >> 6;
  const int waveM = wave >> 1;
  const int waveN = wave & 1;
  const int lm = lane & 15;
  const int kg = lane >> 4;

  const u16* Ab = A + (long)z * sAz + (long)tileM * lda;
  const u16* Bb = Bm + (long)z * sBz + (long)tileN * ldb;

  f32x4 acc[MI][NI];
#pragma unroll
  for (int i = 0; i < MI; ++i)
#pragma unroll
    for (int j = 0; j < NI; ++j) acc[i][j] = (f32x4){0.f, 0.f, 0.f, 0.f};

  for (int kt = 0; kt < K; kt += 32) {
    __syncthreads();
#pragma unroll
    for (int i = 0; i < (BM * 4) / 256; ++i) {
      int c = i * 256 + t;
      async16(Ab + (long)(c >> 2) * lda + kt + (c & 3) * 8, ldsA + (c - lane) * 8);
    }
#pragma unroll
    for (int i = 0; i < (BN * 4) / 256; ++i) {
      int c = i * 256 + t;
      async16(Bb + (long)(c >> 2) * ldb + kt + (c & 3) * 8, ldsB + (c - lane) * 8);
    }
    __syncthreads();

    s16x8 aF[MI], bF[NI];
#pragma unroll
    for (int i = 0; i < MI; ++i)
      aF[i] = *(const s16x8*)&ldsA[(waveM * WTM + i * 16 + lm) * 32 + kg * 8];
#pragma unroll
    for (int j = 0; j < NI; ++j)
      bF[j] = *(const s16x8*)&ldsB[(waveN * WTN + j * 16 + lm) * 32 + kg * 8];
#pragma unroll
    for (int i = 0; i < MI; ++i)
#pragma unroll
      for (int j = 0; j < NI; ++j)
        acc[i][j] = __builtin_amdgcn_mfma_f32_16x16x32_bf16(aF[i], bF[j], acc[i][j], 0, 0, 0);
  }

  if (MODE == 0) {
    // per-wave staged write: no cross-wave barriers in the store phase
    u16* ep = smem + wave * (WTM * EPAD);
    __syncthreads();
#pragma unroll
    for (int i = 0; i < MI; ++i)
#pragma unroll
      for (int j = 0; j < NI; ++j) {
        int n = waveN * WTN + j * 16 + lm;
        float bv = bias ? bias[tileN + n] : 0.0f;
#pragma unroll
        for (int r = 0; r < 4; ++r)
          ep[(i * 16 + kg * 4 + r) * EPAD + j * 16 + lm] = f2bf(acc[i][j][r] * alpha + bv);
      }
    const long Crow = (long)z * sCz + (long)(tileM + waveM * WTM) * ldc + tileN + waveN * WTN;
#pragma unroll
    for (int it = 0; it < (WTM * WTN) / 512; ++it) {
      int idx = it * 64 + lane;
      int row = idx / (WTN / 8), seg = idx % (WTN / 8);
      *(uint4*)&C[Crow + (long)row * ldc + seg * 8] =
          *(const uint4*)&ep[row * EPAD + seg * 8];
    }
  } else {
#pragma unroll
    for (int j = 0; j < NI; ++j) {
      int n = tileN + waveN * WTN + j * 16 + lm;
      float bv = bias ? bias[n] : 0.0f;
#pragma unroll
      for (int i = 0; i < MI; ++i) {
#pragma unroll
        for (int r = 0; r < 4; ++r) {
          int m = tileM + waveM * WTM + i * 16 + kg * 4 + r;
          float v = acc[i][j][r] * alpha + bv;
          int b = m / Lsub, l = m - b * Lsub;
          int h = n >> 6, d = n & 63;
          C[(((long)(b * HH + h) * Lsub + l) << 6) + d] = f2bf(v);
        }
      }
    }
  }
}

// multi-projection: z selects weight/bias/output; z<NPROJ-1 -> head-split [B,H,L,64],
// z==NPROJ-1 -> transposed [B,H,64,L] staged write. K = EE, N = EE.
template<int BM, int BN, int SKIPQ, int NPROJ>
__global__ __launch_bounds__(256, 2)
void gemm_proj(const u16* __restrict__ A,
               const u16* B0, const u16* B1, const u16* B2,
               const float* bias0, const float* bias1, const float* bias2,
               u16* C0, u16* C1, u16* C2,
               int M, int lda, int Lsub, const int* __restrict__ qlen)
{
  constexpr int WTM = BM / 2, WTN = BN / 2;
  constexpr int MI = WTM / 16, NI = WTN / 16;

  const int z = blockIdx.z;
  const int tileM = blockIdx.y * BM;
  const int tileN = blockIdx.x * BN;
  if (SKIPQ == 2) { int b = tileM >> 10; if ((tileM & 1023) >= qlen[b]) return; }

  const u16* Bm = (z == 0) ? B0 : (z == 1) ? B1 : B2;
  const float* bias = (z == 0) ? bias0 : (z == 1) ? bias1 : bias2;
  u16* C = (z == 0) ? C0 : (z == 1) ? C1 : C2;
  const bool tr = (z == NPROJ - 1);

  __shared__ __align__(16) u16 smem[(BM + BN) * 32];
  u16* ldsA = smem;
  u16* ldsB = smem + BM * 32;

  const int t = threadIdx.x;
  const int lane = t & 63;
  const int wave = t >> 6;
  const int waveM = wave >> 1;
  const int waveN = wave & 1;
  const int lm = lane & 15;
  const int kg = lane >> 4;

  const u16* Ab = A + (long)tileM * lda;
  const u16* Bb = Bm + (long)tileN * EE;

  f32x4 acc[MI][NI];
#pragma unroll
  for (int i = 0; i < MI; ++i)
#pragma unroll
    for (int j = 0; j < NI; ++j) acc[i][j] = (f32x4){0.f, 0.f, 0.f, 0.f};

  for (int kt = 0; kt < EE; kt += 32) {
    __syncthreads();
#pragma unroll
    for (int i = 0; i < (BM * 4) / 256; ++i) {
      int c = i * 256 + t;
      async16(Ab + (long)(c >> 2) * lda + kt + (c & 3) * 8, ldsA + (c - lane) * 8);
    }
#pragma unroll
    for (int i = 0; i < (BN * 4) / 256; ++i) {
      int c = i * 256 + t;
      async16(Bb + (long)(c >> 2) * EE + kt + (c & 3) * 8, ldsB + (c - lane) * 8);
    }
    __syncthreads();

    s16x8 aF[MI], bF[NI];
#pragma unroll
    for (int i = 0; i < MI; ++i)
      aF[i] = *(const s16x8*)&ldsA[(waveM * WTM + i * 16 + lm) * 32 + kg * 8];
#pragma unroll
    for (int j = 0; j < NI; ++j)
      bF[j] = *(const s16x8*)&ldsB[(waveN * WTN + j * 16 + lm) * 32 + kg * 8];
#pragma unroll
    for (int i = 0; i < MI; ++i)
#pragma unroll
      for (int j = 0; j < NI; ++j)
        acc[i][j] = __builtin_amdgcn_mfma_f32_16x16x32_bf16(aF[i], bF[j], acc[i][j], 0, 0, 0);
  }

  if (!tr) {
#pragma unroll
    for (int j = 0; j < NI; ++j) {
      int n = tileN + waveN * WTN + j * 16 + lm;
      float bv = bias[n];
#pragma unroll
      for (int i = 0; i < MI; ++i)
#pragma unroll
        for (int r = 0; r < 4; ++r) {
          int m = tileM + waveM * WTM + i * 16 + kg * 4 + r;
          int b = m / Lsub, l = m - b * Lsub;
          int h = n >> 6, d = n & 63;
          C[(((long)(b * HH + h) * Lsub + l) << 6) + d] = f2bf(acc[i][j][r] + bv);
        }
    }
  } else {
    constexpr int PAD = BM + 8;
    const int bb = tileM / Lsub;
    const int l0 = tileM - bb * Lsub;
#pragma unroll
    for (int c = 0; c < BN / 32; ++c) {
      __syncthreads();
#pragma unroll
      for (int j = 0; j < NI; ++j) {
        int nloc = waveN * WTN + j * 16 + lm;
        if (nloc >= c * 32 && nloc < c * 32 + 32) {
          int nl = nloc - c * 32;
          float bv = bias[tileN + nloc];
#pragma unroll
          for (int i = 0; i < MI; ++i)
#pragma unroll
            for (int r = 0; r < 4; ++r) {
              int mm = waveM * WTM + i * 16 + kg * 4 + r;
              smem[nl * PAD + mm] = f2bf(acc[i][j][r] + bv);
            }
        }
      }
      __syncthreads();
#pragma unroll
      for (int v = 0; v < (32 * BM) / (256 * 8); ++v) {
        int idx = v * 256 + t;
        int nl = idx / (BM / 8), m8 = idx % (BM / 8);
        int n = tileN + c * 32 + nl;
        int h = n >> 6, d = n & 63;
        *(uint4*)&C[((long)(bb * HH + h) * HD + d) * Lsub + l0 + m8 * 8] =
            *(const uint4*)&smem[nl * PAD + m8 * 8];
      }
    }
  }
}

// cross softmax stats + head-mean weights (read-only over S)
__global__ __launch_bounds__(256)
void softmax_stats_wmean(const u16* __restrict__ S, float* __restrict__ outw,
                         float2* __restrict__ stats, const int* __restrict__ qlen) {
  int row = blockIdx.x;
  int b = row >> 10, q = row & 1023;
  int t = threadIdx.x, lane = t & 63, w = t >> 6;
  float* wr = outw + (long)row * SLK;
  if (q >= qlen[b]) {
    float4 z = {0.f, 0.f, 0.f, 0.f};
    *(float4*)(wr + t * 8) = z; *(float4*)(wr + t * 8 + 4) = z;
    return;
  }
  __shared__ float acc4[4][2048];
#pragma unroll
  for (int hh = 0; hh < 2; ++hh) {
    int h = 2 * w + hh;
    const u16* p = S + ((long)((b * HH + h) * SLQ + q)) * SLK;
    float x[4][8];
    float m = -1e30f;
#pragma unroll
    for (int c = 0; c < 4; ++c) {
      s16x8 v = *(const s16x8*)(p + c * 512 + lane * 8);
#pragma unroll
      for (int j = 0; j < 8; ++j) { x[c][j] = bf2f((u16)v[j]); m = fmaxf(m, x[c][j]); }
    }
#pragma unroll
    for (int o = 1; o <= 32; o <<= 1) m = fmaxf(m, __shfl_xor(m, o));
    float s = 0.f;
#pragma unroll
    for (int c = 0; c < 4; ++c)
#pragma unroll
      for (int j = 0; j < 8; ++j) { x[c][j] = __expf(x[c][j] - m); s += x[c][j]; }
#pragma unroll
    for (int o = 1; o <= 32; o <<= 1) s += __shfl_xor(s, o);
    if (lane == 0) stats[(long)(b * HH + h) * SLQ + q] = (float2){m, s};
    float sc = 0.125f / s;
#pragma unroll
    for (int c = 0; c < 4; ++c) {
      float4 v0 = {x[c][0] * sc, x[c][1] * sc, x[c][2] * sc, x[c][3] * sc};
      float4 v1 = {x[c][4] * sc, x[c][5] * sc, x[c][6] * sc, x[c][7] * sc};
      if (hh == 0) {
        *(float4*)&acc4[w][c * 512 + lane * 8] = v0;
        *(float4*)&acc4[w][c * 512 + lane * 8 + 4] = v1;
      } else {
        float4 a0 = *(const float4*)&acc4[w][c * 512 + lane * 8];
        float4 a1 = *(const float4*)&acc4[w][c * 512 + lane * 8 + 4];
        a0.x += v0.x; a0.y += v0.y; a0.z += v0.z; a0.w += v0.w;
        a1.x += v1.x; a1.y += v1.y; a1.z += v1.z; a1.w += v1.w;
        *(float4*)&acc4[w][c * 512 + lane * 8] = a0;
        *(float4*)&acc4[w][c * 512 + lane * 8 + 4] = a1;
      }
    }
  }
  __syncthreads();
#pragma unroll
  for (int u = 0; u < 2; ++u) {
    int k = t * 8 + u * 4;
    float4 s0 = *(const float4*)&acc4[0][k];
    float4 s1 = *(const float4*)&acc4[1][k];
    float4 s2 = *(const float4*)&acc4[2][k];
    float4 s3 = *(const float4*)&acc4[3][k];
    float4 o = {s0.x + s1.x + s2.x + s3.x, s0.y + s1.y + s2.y + s3.y,
                s0.z + s1.z + s2.z + s3.z, s0.w + s1.w + s2.w + s3.w};
    *(float4*)(wr + k) = o;
  }
}

// cross PV: direct-global S reads, LDS only for V; bf16 partials
__global__ __launch_bounds__(256, 2)
void pv_cross(const u16* __restrict__ S, const u16* __restrict__ Vt,
              const float2* __restrict__ stats, u16* __restrict__ Opart,
              const int* __restrict__ qlen)
{
  const int qt = blockIdx.x;
  const int bh = blockIdx.y;
  const int kc = blockIdx.z;
  const int b = bh >> 3;
  if (qt * 64 >= qlen[b]) return;

  __shared__ __align__(16) u16 Vl[64 * 136];

  const int t = threadIdx.x, lane = t & 63, w = t >> 6;
  const int lm = lane & 15, quad = lane >> 4;

  const int qrow = qt * 64 + w * 16 + lm;
  const u16* Sb = S + ((long)bh * SLQ + qrow) * SLK;
  const u16* Vb = Vt + (long)bh * HD * SLK;
  const float mrow = stats[(long)bh * SLQ + qrow].x;

  f32x4 O[4];
#pragma unroll
  for (int n = 0; n < 4; ++n) O[n] = (f32x4){0.f, 0.f, 0.f, 0.f};

  for (int ks = 0; ks < 4; ++ks) {
    const int k0 = kc * 512 + ks * 128;
    __syncthreads();
    for (int c = t; c < 1024; c += 256) {
      int d = c >> 4, c16 = c & 15;
      *(uint4*)&Vl[d * 136 + c16 * 8] = *(const uint4*)(Vb + (long)d * SLK + k0 + c16 * 8);
    }
    __syncthreads();
#pragma unroll
    for (int kk = 0; kk < 4; ++kk) {
      s16x8 raw = *(const s16x8*)(Sb + k0 + kk * 32 + quad * 8);
      s16x8 aP;
#pragma unroll
      for (int j = 0; j < 8; ++j)
        aP[j] = (short)f2bf(__expf(bf2f((u16)raw[j]) - mrow));
#pragma unroll
      for (int n = 0; n < 4; ++n) {
        s16x8 bV = *(const s16x8*)&Vl[(n * 16 + lm) * 136 + kk * 32 + quad * 8];
        O[n] = __builtin_amdgcn_mfma_f32_16x16x32_bf16(aP, bV, O[n], 0, 0, 0);
      }
    }
  }

#pragma unroll
  for (int r = 0; r < 4; ++r) {
    int qr2 = qt * 64 + w * 16 + quad * 4 + r;
#pragma unroll
    for (int n = 0; n < 4; ++n)
      Opart[(((long)bh * SLQ + qr2) * 4 + kc) * 64 + n * 16 + lm] = f2bf(O[n][r]);
  }
}

// sum 4 split-K bf16 partials, apply 1/l -> attn bf16
__global__ __launch_bounds__(256)
void pv_combine_cross(const u16* __restrict__ Opart, const float2* __restrict__ stats,
                      u16* __restrict__ attn, const int* __restrict__ qlen)
{
  int gr = blockIdx.x * 16 + (threadIdx.x >> 4);
  int bh = gr >> 10, q = gr & 1023;
  int b = bh >> 3, h = bh & 7;
  if (q >= qlen[b]) return;
  int d = (threadIdx.x & 15) * 4;
  float ax = 0.f, ay = 0.f, az = 0.f, aw = 0.f;
#pragma unroll
  for (int c = 0; c < 4; ++c) {
    const u16* p = Opart + ((long)gr * 4 + c) * 64 + d;
    ax += bf2f(p[0]); ay += bf2f(p[1]); az += bf2f(p[2]); aw += bf2f(p[3]);
  }
  float inv = 1.0f / stats[gr].y;
  unsigned int lo = (unsigned int)f2bf(ax * inv) | ((unsigned int)f2bf(ay * inv) << 16);
  unsigned int hi = (unsigned int)f2bf(az * inv) | ((unsigned int)f2bf(aw * inv) << 16);
  *(uint2*)&attn[((long)b * SLQ + q) * EE + h * HD + d] = (uint2){lo, hi};
}

// self-attention: chunk of 256 keys per block (2 tiles, online softmax), bf16 partials
__global__ __launch_bounds__(256, 3)
void self_flash_chunk(const u16* __restrict__ Qc, const u16* __restrict__ Kc,
                      const u16* __restrict__ Vt, u16* __restrict__ Opart,
                      float2* __restrict__ ml, const int* __restrict__ qlen)
{
  const int qt = blockIdx.x;
  const int bh = blockIdx.y;
  const int ck = blockIdx.z;             // 4 chunks of 256
  const int b = bh >> 3;
  const int kmax = qlen[b];
  if (qt * 64 >= kmax || ck * 256 >= kmax) return;

  __shared__ __align__(16) u16 Kt[128 * 72];
  __shared__ __align__(16) u16 Vl[64 * 136];
  __shared__ __align__(16) u16 Pl[4 * 16 * 136];

  const int t = threadIdx.x, lane = t & 63, w = t >> 6;
  const int col = lane & 15, quad = lane >> 4;

  const u16* Qb = Qc + (long)bh * SLQ * HD;
  const u16* Kb = Kc + (long)bh * SLQ * HD;
  const u16* Vb = Vt + (long)bh * HD * SLQ;

  s16x8 aQ[2];
#pragma unroll
  for (int kk = 0; kk < 2; ++kk)
    aQ[kk] = *(const s16x8*)(Qb + (long)(qt * 64 + w * 16 + col) * HD + kk * 32 + quad * 8);

  f32x4 O[4];
  float mr[4], lr[4];
#pragma unroll
  for (int n = 0; n < 4; ++n) O[n] = (f32x4){0.f, 0.f, 0.f, 0.f};
#pragma unroll
  for (int r = 0; r < 4; ++r) { mr[r] = -1e30f; lr[r] = 0.f; }

  u16* Pw = Pl + w * 16 * 136;

  for (int kt = 0; kt < 2; ++kt) {
    const int k0 = ck * 256 + kt * 128;
    if (k0 >= kmax) break;
    __syncthreads();
    for (int c = t; c < 1024; c += 256) {
      int r = c >> 3, c8 = c & 7;
      *(uint4*)&Kt[r * 72 + c8 * 8] = *(const uint4*)(Kb + (long)(k0 + r) * HD + c8 * 8);
    }
    for (int c = t; c < 1024; c += 256) {
      int d = c >> 4, c16 = c & 15;
      *(uint4*)&Vl[d * 136 + c16 * 8] = *(const uint4*)(Vb + (long)d * SLQ + k0 + c16 * 8);
    }
    __syncthreads();

    f32x4 s[8];
#pragma unroll
    for (int j = 0; j < 8; ++j) s[j] = (f32x4){0.f, 0.f, 0.f, 0.f};
#pragma unroll
    for (int j = 0; j < 8; ++j)
#pragma unroll
      for (int kk = 0; kk < 2; ++kk) {
        s16x8 bK = *(const s16x8*)&Kt[(j * 16 + col) * 72 + kk * 32 + quad * 8];
        s[j] = __builtin_amdgcn_mfma_f32_16x16x32_bf16(aQ[kk], bK, s[j], 0, 0, 0);
      }
#pragma unroll
    for (int j = 0; j < 8; ++j) {
      bool ok = (k0 + j * 16 + col) < kmax;
#pragma unroll
      for (int r = 0; r < 4; ++r)
        s[j][r] = ok ? s[j][r] * 0.125f : -1e30f;
    }
#pragma unroll
    for (int r = 0; r < 4; ++r) {
      float tm = s[0][r];
#pragma unroll
      for (int j = 1; j < 8; ++j) tm = fmaxf(tm, s[j][r]);
#pragma unroll
      for (int o = 1; o <= 8; o <<= 1) tm = fmaxf(tm, __shfl_xor(tm, o));
      float mnew = fmaxf(mr[r], tm);
      float alpha = __expf(mr[r] - mnew);
      mr[r] = mnew;
      float ps = 0.f;
#pragma unroll
      for (int j = 0; j < 8; ++j) {
        float p = __expf(s[j][r] - mnew);
        s[j][r] = p;
        ps += p;
      }
#pragma unroll
      for (int o = 1; o <= 8; o <<= 1) ps += __shfl_xor(ps, o);
      lr[r] = lr[r] * alpha + ps;
#pragma unroll
      for (int n = 0; n < 4; ++n) O[n][r] *= alpha;
    }
#pragma unroll
    for (int j = 0; j < 8; ++j)
#pragma unroll
      for (int r = 0; r < 4; ++r)
        Pw[(quad * 4 + r) * 136 + j * 16 + col] = f2bf(s[j][r]);
#pragma unroll
    for (int kk = 0; kk < 4; ++kk) {
      s16x8 aP = *(const s16x8*)&Pw[col * 136 + kk * 32 + quad * 8];
#pragma unroll
      for (int n = 0; n < 4; ++n) {
        s16x8 bV = *(const s16x8*)&Vl[(n * 16 + col) * 136 + kk * 32 + quad * 8];
        O[n] = __builtin_amdgcn_mfma_f32_16x16x32_bf16(aP, bV, O[n], 0, 0, 0);
      }
    }
  }

#pragma unroll
  for (int r = 0; r < 4; ++r) {
    int q = qt * 64 + w * 16 + quad * 4 + r;
    long gq = (long)bh * SLQ + q;
#pragma unroll
    for (int n = 0; n < 4; ++n)
      Opart[(gq * 4 + ck) * 64 + n * 16 + col] = f2bf(O[n][r]);
    if (col == 0) ml[gq * 4 + ck] = (float2){mr[r], lr[r]};
  }
}

__global__ __launch_bounds__(256)
void self_combine(const u16* __restrict__ Opart, const float2* __restrict__ ml,
                  u16* __restrict__ attn, const int* __restrict__ qlen)
{
  int gr = blockIdx.x * 16 + (threadIdx.x >> 4);
  int bh = gr >> 10, q = gr & 1023;
  int b = bh >> 3, h = bh & 7;
  int kmax = qlen[b];
  if (q >= kmax) return;
  int NC = (kmax + 255) >> 8;
  int d = (threadIdx.x & 15) * 4;
  long base = (long)gr * 4;
  float M = -1e30f;
  for (int c = 0; c < NC; ++c) M = fmaxf(M, ml[base + c].x);
  float L = 0.f;
  float ax = 0.f, ay = 0.f, az = 0.f, aw = 0.f;
  for (int c = 0; c < NC; ++c) {
    float2 st = ml[base + c];
    float wgt = __expf(st.x - M);
    L += st.y * wgt;
    const u16* p = Opart + (base + c) * 64 + d;
    ax += bf2f(p[0]) * wgt; ay += bf2f(p[1]) * wgt;
    az += bf2f(p[2]) * wgt; aw += bf2f(p[3]) * wgt;
  }
  float inv = 1.0f / L;
  unsigned int lo = (unsigned int)f2bf(ax * inv) | ((unsigned int)f2bf(ay * inv) << 16);
  unsigned int hi = (unsigned int)f2bf(az * inv) | ((unsigned int)f2bf(aw * inv) << 16);
  *(uint2*)&attn[((long)b * SLQ + q) * EE + h * HD + d] = (uint2){lo, hi};
}

// fused input conversion: masked queries + keys + 9 weight matrices
__global__ __launch_bounds__(256)
void cvt_all(const float* __restrict__ queries, const float* __restrict__ keys,
             const int* __restrict__ qlen,
             const float* w0, const float* w1, const float* w2, const float* w3,
             const float* w4, const float* w5, const float* w6, const float* w7,
             const float* w8,
             u16* __restrict__ q0, u16* __restrict__ keysb, u16* __restrict__ Wb) {
  int blk = blockIdx.x;
  int t = threadIdx.x;
  const float* src;
  u16* dst;
  long off;
  bool mask = false;
  int b = 0, q = 0;
  if (blk < 1024) {
    off = (long)blk * 2048 + t * 8;
    int row = (int)(off >> 9);
    b = row >> 10; q = row & 1023;
    mask = true;
    src = queries; dst = q0;
  } else if (blk < 3072) {
    off = (long)(blk - 1024) * 2048 + t * 8;
    src = keys; dst = keysb;
  } else {
    int mat = (blk - 3072) >> 7, part = (blk - 3072) & 127;
    const float* srcs[9] = {w0, w1, w2, w3, w4, w5, w6, w7, w8};
    src = srcs[mat];
    off = (long)part * 2048 + t * 8;
    dst = Wb + (long)mat * EE * EE;
  }
  s16x8 o = (s16x8){0, 0, 0, 0, 0, 0, 0, 0};
  if (!mask || q < qlen[b]) {
    float4 a = *(const float4*)&src[off];
    float4 c = *(const float4*)&src[off + 4];
    o[0] = (short)f2bf(a.x); o[1] = (short)f2bf(a.y);
    o[2] = (short)f2bf(a.z); o[3] = (short)f2bf(a.w);
    o[4] = (short)f2bf(c.x); o[5] = (short)f2bf(c.y);
    o[6] = (short)f2bf(c.z); o[7] = (short)f2bf(c.w);
  }
  *(s16x8*)&dst[off] = o;
}

__device__ __forceinline__ float blockSum(float v, float* red4) {
#pragma unroll
  for (int o = 32; o; o >>= 1) v += __shfl_xor(v, o);
  if ((threadIdx.x & 63) == 0) red4[threadIdx.x >> 6] = v;
  __syncthreads();
  v = red4[0] + red4[1] + red4[2] + red4[3];
  __syncthreads();
  return v;
}

template<int OUTF32>
__global__ __launch_bounds__(256)
void silu_ln_kernel(const u16* __restrict__ x1, const u16* __restrict__ x2,
                    const float* __restrict__ g, const float* __restrict__ beta,
                    const int* __restrict__ qlen, void* __restrict__ outv, int mode) {
  int row = blockIdx.x;
  int b = row >> 10, q = row & 1023;
  int t = threadIdx.x;
  if (mode && q >= qlen[b]) {
    if (mode == 1) {
      if (OUTF32) {
        float* o = (float*)outv + (long)row * EE;
        o[2 * t] = 0.f; o[2 * t + 1] = 0.f;
      } else {
        u16* o = (u16*)outv + (long)row * EE;
        *(unsigned int*)&o[2 * t] = 0u;
      }
    }
    return;
  }
  __shared__ float red4[4];
  const u16* p1 = x1 + (long)row * EE;
  const u16* p2 = x2 + (long)row * EE;
  float a0 = bf2f(p1[2 * t]) + bf2f(p2[2 * t]);
  float a1 = bf2f(p1[2 * t + 1]) + bf2f(p2[2 * t + 1]);
  a0 = a0 / (1.f + __expf(-a0));
  a1 = a1 / (1.f + __expf(-a1));
  float mu = blockSum(a0 + a1, red4) * (1.f / 512.f);
  float d0 = a0 - mu, d1 = a1 - mu;
  float var = blockSum(d0 * d0 + d1 * d1, red4) * (1.f / 512.f);
  float rs = rsqrtf(var + 1e-5f);
  float r0 = d0 * rs * g[2 * t] + beta[2 * t];
  float r1 = d1 * rs * g[2 * t + 1] + beta[2 * t + 1];
  if (OUTF32) {
    float* o = (float*)outv + (long)row * EE;
    o[2 * t] = r0; o[2 * t + 1] = r1;
  } else {
    u16* o = (u16*)outv + (long)row * EE;
    o[2 * t] = f2bf(r0); o[2 * t + 1] = f2bf(r1);
  }
}

extern "C" void kernel_launch(void* const* d_in, const int* in_sizes, int n_in,
                              void* d_out, int out_size, void* d_ws, size_t ws_size,
                              hipStream_t stream) {
  const float* queries = (const float*)d_in[0];
  const float* keys    = (const float*)d_in[1];
  const int*   qlen    = (const int*)d_in[2];
  const float* cWq = (const float*)d_in[3],  *cbq = (const float*)d_in[4];
  const float* cWk = (const float*)d_in[5],  *cbk = (const float*)d_in[6];
  const float* cWv = (const float*)d_in[7],  *cbv = (const float*)d_in[8];
  const float* cWo = (const float*)d_in[9],  *cbo = (const float*)d_in[10];
  const float* sWq = (const float*)d_in[11], *sbq = (const float*)d_in[12];
  const float* sWk = (const float*)d_in[13], *sbk = (const float*)d_in[14];
  const float* sWv = (const float*)d_in[15], *sbv = (const float*)d_in[16];
  const float* sWo = (const float*)d_in[17], *sbo = (const float*)d_in[18];
  const float* Wf  = (const float*)d_in[19], *bfb = (const float*)d_in[20];
  const float* g_cross = (const float*)d_in[21], *b_cross = (const float*)d_in[22];
  const float* g_ffn   = (const float*)d_in[23], *b_ffn   = (const float*)d_in[24];
  const float* g_self  = (const float*)d_in[25], *b_self  = (const float*)d_in[26];

  float* out_q = (float*)d_out;
  float* out_w = out_q + (long)BB * SLQ * EE;

  u16* ws = (u16*)d_ws;
  u16* S     = ws;                               // 67,108,864 u16
  u16* Qc    = S   + (long)BB * HH * SLQ * SLK;
  u16* Kc    = Qc  + (long)BB * HH * SLQ * HD;
  u16* Vt    = Kc  + (long)BB * HH * SLK * HD;
  u16* q0    = Vt  + (long)BB * HH * SLK * HD;
  u16* keysb = q0  + (long)BB * SLQ * EE;
  u16* attn  = keysb + (long)BB * SLK * EE;
  u16* proj  = attn + (long)BB * SLQ * EE;
  u16* q1    = proj + (long)BB * SLQ * EE;
  u16* fbuf  = q1  + (long)BB * SLQ * EE;
  u16* q2    = fbuf + (long)BB * SLQ * EE;
  u16* Wb    = q2  + (long)BB * SLQ * EE;
  const long WSLOT = (long)EE * EE;
  u16*    Cpb  = Wb + 9 * WSLOT;                  // cross O partials bf16: 32768*4*64
  float2* stat = (float2*)(Cpb + 8388608);        // 32768 float2

  // self partials overlay S (dead after pv_cross)
  u16*    OpS = S;                                // 32768*4*64 bf16
  float2* mlS = (float2*)(S + 8388608);           // 32768*4 float2

  u16* bWq = Wb + 0 * WSLOT; u16* bWk = Wb + 1 * WSLOT; u16* bWv = Wb + 2 * WSLOT;
  u16* bWo = Wb + 3 * WSLOT; u16* bsWq = Wb + 4 * WSLOT; u16* bsWk = Wb + 5 * WSLOT;
  u16* bsWv = Wb + 6 * WSLOT; u16* bsWo = Wb + 7 * WSLOT; u16* bWf = Wb + 8 * WSLOT;

  dim3 blk(256);
  const int MQ = BB * SLQ;   // 4096
  const int MK = BB * SLK;   // 8192

  cvt_all<<<dim3(3072 + 9 * 128), blk, 0, stream>>>(
      queries, keys, qlen, cWq, cWk, cWv, cWo, sWq, sWk, sWv, sWo, Wf, q0, keysb, Wb);

  // cross Q projection
  gemm_nt<64, 64, 1, 2><<<dim3(EE / 64, MQ / 64, 1), blk, 0, stream>>>(
      q0, bWq, cbq, Qc, MQ, EE, EE, EE, EE, 0, 0, 0, 0, 1.0f, SLQ, qlen);
  // cross K+V projections in one dispatch
  gemm_proj<64, 64, 0, 2><<<dim3(EE / 64, MK / 64, 2), blk, 0, stream>>>(
      keysb, bWk, bWv, nullptr, cbk, cbv, nullptr, Kc, Vt, nullptr, MK, EE, SLK, qlen);

  // S = Q K^T * 1/8
  gemm_nt<128, 128, 0, 1><<<dim3(SLK / 128, SLQ / 128, BB * HH), blk, 0, stream>>>(
      Qc, Kc, nullptr, S, SLQ, SLK, HD, HD, HD, SLK,
      (long)SLQ * HD, (long)SLK * HD, (long)SLQ * SLK, 0.125f, 0, qlen);

  softmax_stats_wmean<<<dim3(BB * SLQ), blk, 0, stream>>>(S, out_w, stat, qlen);

  pv_cross<<<dim3(16, 32, 4), blk, 0, stream>>>(S, Vt, stat, Cpb, qlen);
  pv_combine_cross<<<dim3(2048), blk, 0, stream>>>(Cpb, stat, attn, qlen);

  gemm_nt<64, 64, 0, 2><<<dim3(EE / 64, MQ / 64, 1), blk, 0, stream>>>(
      attn, bWo, cbo, proj, MQ, EE, EE, EE, EE, EE, 0, 0, 0, 1.0f, SLQ, qlen);

  silu_ln_kernel<0><<<dim3(MQ), blk, 0, stream>>>(proj, q0, g_cross, b_cross, qlen, q1, 2);

  gemm_nt<64, 64, 0, 2><<<dim3(EE / 64, MQ / 64, 1), blk, 0, stream>>>(
      q1, bWf, bfb, fbuf, MQ, EE, EE, EE, EE, EE, 0, 0, 0, 1.0f, SLQ, qlen);

  silu_ln_kernel<0><<<dim3(MQ), blk, 0, stream>>>(q1, fbuf, g_ffn, b_ffn, qlen, q2, 1);

  // self Q/K/V projections in one dispatch
  gemm_proj<64, 64, 2, 3><<<dim3(EE / 64, MQ / 64, 3), blk, 0, stream>>>(
      q2, bsWq, bsWk, bsWv, sbq, sbk, sbv, Qc, Kc, Vt, MQ, EE, SLQ, qlen);

  // fused self attention (partials overlay S)
  self_flash_chunk<<<dim3(16, 32, 4), blk, 0, stream>>>(Qc, Kc, Vt, OpS, mlS, qlen);
  self_combine<<<dim3(2048), blk, 0, stream>>>(OpS, mlS, attn, qlen);

  gemm_nt<64, 64, 0, 2><<<dim3(EE / 64, MQ / 64, 1), blk, 0, stream>>>(
      attn, bsWo, sbo, proj, MQ, EE, EE, EE, EE, EE, 0, 0, 0, 1.0f, SLQ, qlen);

  silu_ln_kernel<1><<<dim3(MQ), blk, 0, stream>>>(q2, proj, g_self, b_self, qlen, out_q, 1);
}

// Round 9
// 319.616 us; speedup vs baseline: 1.2623x; 1.0024x over previous
//
#include <hip/hip_runtime.h>

#define BB 4
#define SLQ 1024
#define SLK 2048
#define EE 512
#define HH 8
#define HD 64

typedef unsigned short u16;
typedef __attribute__((ext_vector_type(8))) short s16x8;
typedef __attribute__((ext_vector_type(4))) float f32x4;

__device__ __forceinline__ float bf2f(u16 u) {
  union { unsigned int i; float f; } v; v.i = ((unsigned int)u) << 16; return v.f;
}
__device__ __forceinline__ u16 f2bf(float f) {
  union { float f; unsigned int i; } v; v.f = f;
  unsigned int i = v.i;
  return (u16)((i + 0x7fffu + ((i >> 16) & 1u)) >> 16);
}

__device__ __forceinline__ void async16(const u16* g, u16* l) {
  __builtin_amdgcn_global_load_lds(
      (const __attribute__((address_space(1))) unsigned int*)g,
      (__attribute__((address_space(3))) unsigned int*)l, 16, 0, 0);
}

// NT GEMM: C[m,n] = alpha*sum_k A[m,k]*B[n,k] + bias[n]
// MODE 0: row-major, per-wave barrier-free staged write
// MODE 1: head-split [B,H,Lsub,64] direct scatter
// SKIPQ 0: none; 1: b=z>>3, skip tileM>=qlen[b]; 2: b=tileM>>10 (Lsub=1024)
template<int BM, int BN, int MODE, int SKIPQ>
__global__ __launch_bounds__(256, (BM == 128 ? 4 : 6))
void gemm_nt(const u16* __restrict__ A, const u16* __restrict__ Bm,
             const float* __restrict__ bias, u16* __restrict__ C,
             int M, int N, int K, int lda, int ldb, int ldc,
             long sAz, long sBz, long sCz, float alpha, int Lsub,
             const int* __restrict__ qlen)
{
  constexpr int WTM = BM / 2, WTN = BN / 2;
  constexpr int MI = WTM / 16, NI = WTN / 16;
  constexpr int EPAD = WTN + 8;
  constexpr int SM1 = (BM + BN) * 32;
  constexpr int SM2 = (MODE == 0) ? 4 * WTM * EPAD : 0;
  constexpr int SM = (SM1 > SM2) ? SM1 : SM2;

  const int z = blockIdx.z;
  const int tileM = blockIdx.y * BM;
  const int tileN = blockIdx.x * BN;

  if (SKIPQ == 1) { if (tileM >= qlen[z >> 3]) return; }
  if (SKIPQ == 2) { int b = tileM >> 10; if ((tileM & 1023) >= qlen[b]) return; }

  __shared__ __align__(16) u16 smem[SM];
  u16* ldsA = smem;
  u16* ldsB = smem + BM * 32;

  const int t = threadIdx.x;
  const int lane = t & 63;
  const int wave = t >> 6;
  const int waveM = wave >> 1;
  const int waveN = wave & 1;
  const int lm = lane & 15;
  const int kg = lane >> 4;

  const u16* Ab = A + (long)z * sAz + (long)tileM * lda;
  const u16* Bb = Bm + (long)z * sBz + (long)tileN * ldb;

  f32x4 acc[MI][NI];
#pragma unroll
  for (int i = 0; i < MI; ++i)
#pragma unroll
    for (int j = 0; j < NI; ++j) acc[i][j] = (f32x4){0.f, 0.f, 0.f, 0.f};

  for (int kt = 0; kt < K; kt += 32) {
    __syncthreads();
#pragma unroll
    for (int i = 0; i < (BM * 4) / 256; ++i) {
      int c = i * 256 + t;
      async16(Ab + (long)(c >> 2) * lda + kt + (c & 3) * 8, ldsA + (c - lane) * 8);
    }
#pragma unroll
    for (int i = 0; i < (BN * 4) / 256; ++i) {
      int c = i * 256 + t;
      async16(Bb + (long)(c >> 2) * ldb + kt + (c & 3) * 8, ldsB + (c - lane) * 8);
    }
    __syncthreads();

    s16x8 aF[MI], bF[NI];
#pragma unroll
    for (int i = 0; i < MI; ++i)
      aF[i] = *(const s16x8*)&ldsA[(waveM * WTM + i * 16 + lm) * 32 + kg * 8];
#pragma unroll
    for (int j = 0; j < NI; ++j)
      bF[j] = *(const s16x8*)&ldsB[(waveN * WTN + j * 16 + lm) * 32 + kg * 8];
#pragma unroll
    for (int i = 0; i < MI; ++i)
#pragma unroll
      for (int j = 0; j < NI; ++j)
        acc[i][j] = __builtin_amdgcn_mfma_f32_16x16x32_bf16(aF[i], bF[j], acc[i][j], 0, 0, 0);
  }

  if (MODE == 0) {
    // per-wave staged write: no cross-wave barriers in the store phase
    u16* ep = smem + wave * (WTM * EPAD);
    __syncthreads();
#pragma unroll
    for (int i = 0; i < MI; ++i)
#pragma unroll
      for (int j = 0; j < NI; ++j) {
        int n = waveN * WTN + j * 16 + lm;
        float bv = bias ? bias[tileN + n] : 0.0f;
#pragma unroll
        for (int r = 0; r < 4; ++r)
          ep[(i * 16 + kg * 4 + r) * EPAD + j * 16 + lm] = f2bf(acc[i][j][r] * alpha + bv);
      }
    const long Crow = (long)z * sCz + (long)(tileM + waveM * WTM) * ldc + tileN + waveN * WTN;
#pragma unroll
    for (int it = 0; it < (WTM * WTN) / 512; ++it) {
      int idx = it * 64 + lane;
      int row = idx / (WTN / 8), seg = idx % (WTN / 8);
      *(uint4*)&C[Crow + (long)row * ldc + seg * 8] =
          *(const uint4*)&ep[row * EPAD + seg * 8];
    }
  } else {
#pragma unroll
    for (int j = 0; j < NI; ++j) {
      int n = tileN + waveN * WTN + j * 16 + lm;
      float bv = bias ? bias[n] : 0.0f;
#pragma unroll
      for (int i = 0; i < MI; ++i) {
#pragma unroll
        for (int r = 0; r < 4; ++r) {
          int m = tileM + waveM * WTM + i * 16 + kg * 4 + r;
          float v = acc[i][j][r] * alpha + bv;
          int b = m / Lsub, l = m - b * Lsub;
          int h = n >> 6, d = n & 63;
          C[(((long)(b * HH + h) * Lsub + l) << 6) + d] = f2bf(v);
        }
      }
    }
  }
}

// multi-projection: z selects weight/bias/output; z<NPROJ-1 -> head-split [B,H,L,64],
// z==NPROJ-1 -> transposed [B,H,64,L] staged write. K = EE, N = EE.
template<int BM, int BN, int SKIPQ, int NPROJ>
__global__ __launch_bounds__(256, 6)
void gemm_proj(const u16* __restrict__ A,
               const u16* B0, const u16* B1, const u16* B2,
               const float* bias0, const float* bias1, const float* bias2,
               u16* C0, u16* C1, u16* C2,
               int M, int lda, int Lsub, const int* __restrict__ qlen)
{
  constexpr int WTM = BM / 2, WTN = BN / 2;
  constexpr int MI = WTM / 16, NI = WTN / 16;

  const int z = blockIdx.z;
  const int tileM = blockIdx.y * BM;
  const int tileN = blockIdx.x * BN;
  if (SKIPQ == 2) { int b = tileM >> 10; if ((tileM & 1023) >= qlen[b]) return; }

  const u16* Bm = (z == 0) ? B0 : (z == 1) ? B1 : B2;
  const float* bias = (z == 0) ? bias0 : (z == 1) ? bias1 : bias2;
  u16* C = (z == 0) ? C0 : (z == 1) ? C1 : C2;
  const bool tr = (z == NPROJ - 1);

  __shared__ __align__(16) u16 smem[(BM + BN) * 32];
  u16* ldsA = smem;
  u16* ldsB = smem + BM * 32;

  const int t = threadIdx.x;
  const int lane = t & 63;
  const int wave = t >> 6;
  const int waveM = wave >> 1;
  const int waveN = wave & 1;
  const int lm = lane & 15;
  const int kg = lane >> 4;

  const u16* Ab = A + (long)tileM * lda;
  const u16* Bb = Bm + (long)tileN * EE;

  f32x4 acc[MI][NI];
#pragma unroll
  for (int i = 0; i < MI; ++i)
#pragma unroll
    for (int j = 0; j < NI; ++j) acc[i][j] = (f32x4){0.f, 0.f, 0.f, 0.f};

  for (int kt = 0; kt < EE; kt += 32) {
    __syncthreads();
#pragma unroll
    for (int i = 0; i < (BM * 4) / 256; ++i) {
      int c = i * 256 + t;
      async16(Ab + (long)(c >> 2) * lda + kt + (c & 3) * 8, ldsA + (c - lane) * 8);
    }
#pragma unroll
    for (int i = 0; i < (BN * 4) / 256; ++i) {
      int c = i * 256 + t;
      async16(Bb + (long)(c >> 2) * EE + kt + (c & 3) * 8, ldsB + (c - lane) * 8);
    }
    __syncthreads();

    s16x8 aF[MI], bF[NI];
#pragma unroll
    for (int i = 0; i < MI; ++i)
      aF[i] = *(const s16x8*)&ldsA[(waveM * WTM + i * 16 + lm) * 32 + kg * 8];
#pragma unroll
    for (int j = 0; j < NI; ++j)
      bF[j] = *(const s16x8*)&ldsB[(waveN * WTN + j * 16 + lm) * 32 + kg * 8];
#pragma unroll
    for (int i = 0; i < MI; ++i)
#pragma unroll
      for (int j = 0; j < NI; ++j)
        acc[i][j] = __builtin_amdgcn_mfma_f32_16x16x32_bf16(aF[i], bF[j], acc[i][j], 0, 0, 0);
  }

  if (!tr) {
#pragma unroll
    for (int j = 0; j < NI; ++j) {
      int n = tileN + waveN * WTN + j * 16 + lm;
      float bv = bias[n];
#pragma unroll
      for (int i = 0; i < MI; ++i)
#pragma unroll
        for (int r = 0; r < 4; ++r) {
          int m = tileM + waveM * WTM + i * 16 + kg * 4 + r;
          int b = m / Lsub, l = m - b * Lsub;
          int h = n >> 6, d = n & 63;
          C[(((long)(b * HH + h) * Lsub + l) << 6) + d] = f2bf(acc[i][j][r] + bv);
        }
    }
  } else {
    constexpr int PAD = BM + 8;
    const int bb = tileM / Lsub;
    const int l0 = tileM - bb * Lsub;
#pragma unroll
    for (int c = 0; c < BN / 32; ++c) {
      __syncthreads();
#pragma unroll
      for (int j = 0; j < NI; ++j) {
        int nloc = waveN * WTN + j * 16 + lm;
        if (nloc >= c * 32 && nloc < c * 32 + 32) {
          int nl = nloc - c * 32;
          float bv = bias[tileN + nloc];
#pragma unroll
          for (int i = 0; i < MI; ++i)
#pragma unroll
            for (int r = 0; r < 4; ++r) {
              int mm = waveM * WTM + i * 16 + kg * 4 + r;
              smem[nl * PAD + mm] = f2bf(acc[i][j][r] + bv);
            }
        }
      }
      __syncthreads();
#pragma unroll
      for (int v = 0; v < (32 * BM) / (256 * 8); ++v) {
        int idx = v * 256 + t;
        int nl = idx / (BM / 8), m8 = idx % (BM / 8);
        int n = tileN + c * 32 + nl;
        int h = n >> 6, d = n & 63;
        *(uint4*)&C[((long)(bb * HH + h) * HD + d) * Lsub + l0 + m8 * 8] =
            *(const uint4*)&smem[nl * PAD + m8 * 8];
      }
    }
  }
}

// cross softmax stats + head-mean weights (read-only over S)
__global__ __launch_bounds__(256)
void softmax_stats_wmean(const u16* __restrict__ S, float* __restrict__ outw,
                         float2* __restrict__ stats, const int* __restrict__ qlen) {
  int row = blockIdx.x;
  int b = row >> 10, q = row & 1023;
  int t = threadIdx.x, lane = t & 63, w = t >> 6;
  float* wr = outw + (long)row * SLK;
  if (q >= qlen[b]) {
    float4 z = {0.f, 0.f, 0.f, 0.f};
    *(float4*)(wr + t * 8) = z; *(float4*)(wr + t * 8 + 4) = z;
    return;
  }
  __shared__ float acc4[4][2048];
#pragma unroll
  for (int hh = 0; hh < 2; ++hh) {
    int h = 2 * w + hh;
    const u16* p = S + ((long)((b * HH + h) * SLQ + q)) * SLK;
    float x[4][8];
    float m = -1e30f;
#pragma unroll
    for (int c = 0; c < 4; ++c) {
      s16x8 v = *(const s16x8*)(p + c * 512 + lane * 8);
#pragma unroll
      for (int j = 0; j < 8; ++j) { x[c][j] = bf2f((u16)v[j]); m = fmaxf(m, x[c][j]); }
    }
#pragma unroll
    for (int o = 1; o <= 32; o <<= 1) m = fmaxf(m, __shfl_xor(m, o));
    float s = 0.f;
#pragma unroll
    for (int c = 0; c < 4; ++c)
#pragma unroll
      for (int j = 0; j < 8; ++j) { x[c][j] = __expf(x[c][j] - m); s += x[c][j]; }
#pragma unroll
    for (int o = 1; o <= 32; o <<= 1) s += __shfl_xor(s, o);
    if (lane == 0) stats[(long)(b * HH + h) * SLQ + q] = (float2){m, s};
    float sc = 0.125f / s;
#pragma unroll
    for (int c = 0; c < 4; ++c) {
      float4 v0 = {x[c][0] * sc, x[c][1] * sc, x[c][2] * sc, x[c][3] * sc};
      float4 v1 = {x[c][4] * sc, x[c][5] * sc, x[c][6] * sc, x[c][7] * sc};
      if (hh == 0) {
        *(float4*)&acc4[w][c * 512 + lane * 8] = v0;
        *(float4*)&acc4[w][c * 512 + lane * 8 + 4] = v1;
      } else {
        float4 a0 = *(const float4*)&acc4[w][c * 512 + lane * 8];
        float4 a1 = *(const float4*)&acc4[w][c * 512 + lane * 8 + 4];
        a0.x += v0.x; a0.y += v0.y; a0.z += v0.z; a0.w += v0.w;
        a1.x += v1.x; a1.y += v1.y; a1.z += v1.z; a1.w += v1.w;
        *(float4*)&acc4[w][c * 512 + lane * 8] = a0;
        *(float4*)&acc4[w][c * 512 + lane * 8 + 4] = a1;
      }
    }
  }
  __syncthreads();
#pragma unroll
  for (int u = 0; u < 2; ++u) {
    int k = t * 8 + u * 4;
    float4 s0 = *(const float4*)&acc4[0][k];
    float4 s1 = *(const float4*)&acc4[1][k];
    float4 s2 = *(const float4*)&acc4[2][k];
    float4 s3 = *(const float4*)&acc4[3][k];
    float4 o = {s0.x + s1.x + s2.x + s3.x, s0.y + s1.y + s2.y + s3.y,
                s0.z + s1.z + s2.z + s3.z, s0.w + s1.w + s2.w + s3.w};
    *(float4*)(wr + k) = o;
  }
}

// cross PV: direct-global S reads, LDS only for V; bf16 partials
__global__ __launch_bounds__(256, 6)
void pv_cross(const u16* __restrict__ S, const u16* __restrict__ Vt,
              const float2* __restrict__ stats, u16* __restrict__ Opart,
              const int* __restrict__ qlen)
{
  const int qt = blockIdx.x;
  const int bh = blockIdx.y;
  const int kc = blockIdx.z;
  const int b = bh >> 3;
  if (qt * 64 >= qlen[b]) return;

  __shared__ __align__(16) u16 Vl[64 * 136];

  const int t = threadIdx.x, lane = t & 63, w = t >> 6;
  const int lm = lane & 15, quad = lane >> 4;

  const int qrow = qt * 64 + w * 16 + lm;
  const u16* Sb = S + ((long)bh * SLQ + qrow) * SLK;
  const u16* Vb = Vt + (long)bh * HD * SLK;
  const float mrow = stats[(long)bh * SLQ + qrow].x;

  f32x4 O[4];
#pragma unroll
  for (int n = 0; n < 4; ++n) O[n] = (f32x4){0.f, 0.f, 0.f, 0.f};

  for (int ks = 0; ks < 4; ++ks) {
    const int k0 = kc * 512 + ks * 128;
    __syncthreads();
    for (int c = t; c < 1024; c += 256) {
      int d = c >> 4, c16 = c & 15;
      *(uint4*)&Vl[d * 136 + c16 * 8] = *(const uint4*)(Vb + (long)d * SLK + k0 + c16 * 8);
    }
    __syncthreads();
#pragma unroll
    for (int kk = 0; kk < 4; ++kk) {
      s16x8 raw = *(const s16x8*)(Sb + k0 + kk * 32 + quad * 8);
      s16x8 aP;
#pragma unroll
      for (int j = 0; j < 8; ++j)
        aP[j] = (short)f2bf(__expf(bf2f((u16)raw[j]) - mrow));
#pragma unroll
      for (int n = 0; n < 4; ++n) {
        s16x8 bV = *(const s16x8*)&Vl[(n * 16 + lm) * 136 + kk * 32 + quad * 8];
        O[n] = __builtin_amdgcn_mfma_f32_16x16x32_bf16(aP, bV, O[n], 0, 0, 0);
      }
    }
  }

#pragma unroll
  for (int r = 0; r < 4; ++r) {
    int qr2 = qt * 64 + w * 16 + quad * 4 + r;
#pragma unroll
    for (int n = 0; n < 4; ++n)
      Opart[(((long)bh * SLQ + qr2) * 4 + kc) * 64 + n * 16 + lm] = f2bf(O[n][r]);
  }
}

// sum 4 split-K bf16 partials, apply 1/l -> attn bf16
__global__ __launch_bounds__(256)
void pv_combine_cross(const u16* __restrict__ Opart, const float2* __restrict__ stats,
                      u16* __restrict__ attn, const int* __restrict__ qlen)
{
  int gr = blockIdx.x * 16 + (threadIdx.x >> 4);
  int bh = gr >> 10, q = gr & 1023;
  int b = bh >> 3, h = bh & 7;
  if (q >= qlen[b]) return;
  int d = (threadIdx.x & 15) * 4;
  float ax = 0.f, ay = 0.f, az = 0.f, aw = 0.f;
#pragma unroll
  for (int c = 0; c < 4; ++c) {
    const u16* p = Opart + ((long)gr * 4 + c) * 64 + d;
    ax += bf2f(p[0]); ay += bf2f(p[1]); az += bf2f(p[2]); aw += bf2f(p[3]);
  }
  float inv = 1.0f / stats[gr].y;
  unsigned int lo = (unsigned int)f2bf(ax * inv) | ((unsigned int)f2bf(ay * inv) << 16);
  unsigned int hi = (unsigned int)f2bf(az * inv) | ((unsigned int)f2bf(aw * inv) << 16);
  *(uint2*)&attn[((long)b * SLQ + q) * EE + h * HD + d] = (uint2){lo, hi};
}

// self-attention: chunk of 256 keys per block (2 tiles, online softmax), bf16 partials
__global__ __launch_bounds__(256, 3)
void self_flash_chunk(const u16* __restrict__ Qc, const u16* __restrict__ Kc,
                      const u16* __restrict__ Vt, u16* __restrict__ Opart,
                      float2* __restrict__ ml, const int* __restrict__ qlen)
{
  const int qt = blockIdx.x;
  const int bh = blockIdx.y;
  const int ck = blockIdx.z;             // 4 chunks of 256
  const int b = bh >> 3;
  const int kmax = qlen[b];
  if (qt * 64 >= kmax || ck * 256 >= kmax) return;

  __shared__ __align__(16) u16 Kt[128 * 72];
  __shared__ __align__(16) u16 Vl[64 * 136];
  __shared__ __align__(16) u16 Pl[4 * 16 * 136];

  const int t = threadIdx.x, lane = t & 63, w = t >> 6;
  const int col = lane & 15, quad = lane >> 4;

  const u16* Qb = Qc + (long)bh * SLQ * HD;
  const u16* Kb = Kc + (long)bh * SLQ * HD;
  const u16* Vb = Vt + (long)bh * HD * SLQ;

  s16x8 aQ[2];
#pragma unroll
  for (int kk = 0; kk < 2; ++kk)
    aQ[kk] = *(const s16x8*)(Qb + (long)(qt * 64 + w * 16 + col) * HD + kk * 32 + quad * 8);

  f32x4 O[4];
  float mr[4], lr[4];
#pragma unroll
  for (int n = 0; n < 4; ++n) O[n] = (f32x4){0.f, 0.f, 0.f, 0.f};
#pragma unroll
  for (int r = 0; r < 4; ++r) { mr[r] = -1e30f; lr[r] = 0.f; }

  u16* Pw = Pl + w * 16 * 136;

  for (int kt = 0; kt < 2; ++kt) {
    const int k0 = ck * 256 + kt * 128;
    if (k0 >= kmax) break;
    __syncthreads();
    for (int c = t; c < 1024; c += 256) {
      int r = c >> 3, c8 = c & 7;
      *(uint4*)&Kt[r * 72 + c8 * 8] = *(const uint4*)(Kb + (long)(k0 + r) * HD + c8 * 8);
    }
    for (int c = t; c < 1024; c += 256) {
      int d = c >> 4, c16 = c & 15;
      *(uint4*)&Vl[d * 136 + c16 * 8] = *(const uint4*)(Vb + (long)d * SLQ + k0 + c16 * 8);
    }
    __syncthreads();

    f32x4 s[8];
#pragma unroll
    for (int j = 0; j < 8; ++j) s[j] = (f32x4){0.f, 0.f, 0.f, 0.f};
#pragma unroll
    for (int j = 0; j < 8; ++j)
#pragma unroll
      for (int kk = 0; kk < 2; ++kk) {
        s16x8 bK = *(const s16x8*)&Kt[(j * 16 + col) * 72 + kk * 32 + quad * 8];
        s[j] = __builtin_amdgcn_mfma_f32_16x16x32_bf16(aQ[kk], bK, s[j], 0, 0, 0);
      }
#pragma unroll
    for (int j = 0; j < 8; ++j) {
      bool ok = (k0 + j * 16 + col) < kmax;
#pragma unroll
      for (int r = 0; r < 4; ++r)
        s[j][r] = ok ? s[j][r] * 0.125f : -1e30f;
    }
#pragma unroll
    for (int r = 0; r < 4; ++r) {
      float tm = s[0][r];
#pragma unroll
      for (int j = 1; j < 8; ++j) tm = fmaxf(tm, s[j][r]);
#pragma unroll
      for (int o = 1; o <= 8; o <<= 1) tm = fmaxf(tm, __shfl_xor(tm, o));
      float mnew = fmaxf(mr[r], tm);
      float alpha = __expf(mr[r] - mnew);
      mr[r] = mnew;
      float ps = 0.f;
#pragma unroll
      for (int j = 0; j < 8; ++j) {
        float p = __expf(s[j][r] - mnew);
        s[j][r] = p;
        ps += p;
      }
#pragma unroll
      for (int o = 1; o <= 8; o <<= 1) ps += __shfl_xor(ps, o);
      lr[r] = lr[r] * alpha + ps;
#pragma unroll
      for (int n = 0; n < 4; ++n) O[n][r] *= alpha;
    }
#pragma unroll
    for (int j = 0; j < 8; ++j)
#pragma unroll
      for (int r = 0; r < 4; ++r)
        Pw[(quad * 4 + r) * 136 + j * 16 + col] = f2bf(s[j][r]);
#pragma unroll
    for (int kk = 0; kk < 4; ++kk) {
      s16x8 aP = *(const s16x8*)&Pw[col * 136 + kk * 32 + quad * 8];
#pragma unroll
      for (int n = 0; n < 4; ++n) {
        s16x8 bV = *(const s16x8*)&Vl[(n * 16 + col) * 136 + kk * 32 + quad * 8];
        O[n] = __builtin_amdgcn_mfma_f32_16x16x32_bf16(aP, bV, O[n], 0, 0, 0);
      }
    }
  }

#pragma unroll
  for (int r = 0; r < 4; ++r) {
    int q = qt * 64 + w * 16 + quad * 4 + r;
    long gq = (long)bh * SLQ + q;
#pragma unroll
    for (int n = 0; n < 4; ++n)
      Opart[(gq * 4 + ck) * 64 + n * 16 + col] = f2bf(O[n][r]);
    if (col == 0) ml[gq * 4 + ck] = (float2){mr[r], lr[r]};
  }
}

__global__ __launch_bounds__(256)
void self_combine(const u16* __restrict__ Opart, const float2* __restrict__ ml,
                  u16* __restrict__ attn, const int* __restrict__ qlen)
{
  int gr = blockIdx.x * 16 + (threadIdx.x >> 4);
  int bh = gr >> 10, q = gr & 1023;
  int b = bh >> 3, h = bh & 7;
  int kmax = qlen[b];
  if (q >= kmax) return;
  int NC = (kmax + 255) >> 8;
  int d = (threadIdx.x & 15) * 4;
  long base = (long)gr * 4;
  float M = -1e30f;
  for (int c = 0; c < NC; ++c) M = fmaxf(M, ml[base + c].x);
  float L = 0.f;
  float ax = 0.f, ay = 0.f, az = 0.f, aw = 0.f;
  for (int c = 0; c < NC; ++c) {
    float2 st = ml[base + c];
    float wgt = __expf(st.x - M);
    L += st.y * wgt;
    const u16* p = Opart + (base + c) * 64 + d;
    ax += bf2f(p[0]) * wgt; ay += bf2f(p[1]) * wgt;
    az += bf2f(p[2]) * wgt; aw += bf2f(p[3]) * wgt;
  }
  float inv = 1.0f / L;
  unsigned int lo = (unsigned int)f2bf(ax * inv) | ((unsigned int)f2bf(ay * inv) << 16);
  unsigned int hi = (unsigned int)f2bf(az * inv) | ((unsigned int)f2bf(aw * inv) << 16);
  *(uint2*)&attn[((long)b * SLQ + q) * EE + h * HD + d] = (uint2){lo, hi};
}

// fused input conversion: masked queries + keys + 9 weight matrices
__global__ __launch_bounds__(256)
void cvt_all(const float* __restrict__ queries, const float* __restrict__ keys,
             const int* __restrict__ qlen,
             const float* w0, const float* w1, const float* w2, const float* w3,
             const float* w4, const float* w5, const float* w6, const float* w7,
             const float* w8,
             u16* __restrict__ q0, u16* __restrict__ keysb, u16* __restrict__ Wb) {
  int blk = blockIdx.x;
  int t = threadIdx.x;
  const float* src;
  u16* dst;
  long off;
  bool mask = false;
  int b = 0, q = 0;
  if (blk < 1024) {
    off = (long)blk * 2048 + t * 8;
    int row = (int)(off >> 9);
    b = row >> 10; q = row & 1023;
    mask = true;
    src = queries; dst = q0;
  } else if (blk < 3072) {
    off = (long)(blk - 1024) * 2048 + t * 8;
    src = keys; dst = keysb;
  } else {
    int mat = (blk - 3072) >> 7, part = (blk - 3072) & 127;
    const float* srcs[9] = {w0, w1, w2, w3, w4, w5, w6, w7, w8};
    src = srcs[mat];
    off = (long)part * 2048 + t * 8;
    dst = Wb + (long)mat * EE * EE;
  }
  s16x8 o = (s16x8){0, 0, 0, 0, 0, 0, 0, 0};
  if (!mask || q < qlen[b]) {
    float4 a = *(const float4*)&src[off];
    float4 c = *(const float4*)&src[off + 4];
    o[0] = (short)f2bf(a.x); o[1] = (short)f2bf(a.y);
    o[2] = (short)f2bf(a.z); o[3] = (short)f2bf(a.w);
    o[4] = (short)f2bf(c.x); o[5] = (short)f2bf(c.y);
    o[6] = (short)f2bf(c.z); o[7] = (short)f2bf(c.w);
  }
  *(s16x8*)&dst[off] = o;
}

__device__ __forceinline__ float blockSum(float v, float* red4) {
#pragma unroll
  for (int o = 32; o; o >>= 1) v += __shfl_xor(v, o);
  if ((threadIdx.x & 63) == 0) red4[threadIdx.x >> 6] = v;
  __syncthreads();
  v = red4[0] + red4[1] + red4[2] + red4[3];
  __syncthreads();
  return v;
}

template<int OUTF32>
__global__ __launch_bounds__(256)
void silu_ln_kernel(const u16* __restrict__ x1, const u16* __restrict__ x2,
                    const float* __restrict__ g, const float* __restrict__ beta,
                    const int* __restrict__ qlen, void* __restrict__ outv, int mode) {
  int row = blockIdx.x;
  int b = row >> 10, q = row & 1023;
  int t = threadIdx.x;
  if (mode && q >= qlen[b]) {
    if (mode == 1) {
      if (OUTF32) {
        float* o = (float*)outv + (long)row * EE;
        o[2 * t] = 0.f; o[2 * t + 1] = 0.f;
      } else {
        u16* o = (u16*)outv + (long)row * EE;
        *(unsigned int*)&o[2 * t] = 0u;
      }
    }
    return;
  }
  __shared__ float red4[4];
  const u16* p1 = x1 + (long)row * EE;
  const u16* p2 = x2 + (long)row * EE;
  float a0 = bf2f(p1[2 * t]) + bf2f(p2[2 * t]);
  float a1 = bf2f(p1[2 * t + 1]) + bf2f(p2[2 * t + 1]);
  a0 = a0 / (1.f + __expf(-a0));
  a1 = a1 / (1.f + __expf(-a1));
  float mu = blockSum(a0 + a1, red4) * (1.f / 512.f);
  float d0 = a0 - mu, d1 = a1 - mu;
  float var = blockSum(d0 * d0 + d1 * d1, red4) * (1.f / 512.f);
  float rs = rsqrtf(var + 1e-5f);
  float r0 = d0 * rs * g[2 * t] + beta[2 * t];
  float r1 = d1 * rs * g[2 * t + 1] + beta[2 * t + 1];
  if (OUTF32) {
    float* o = (float*)outv + (long)row * EE;
    o[2 * t] = r0; o[2 * t + 1] = r1;
  } else {
    u16* o = (u16*)outv + (long)row * EE;
    o[2 * t] = f2bf(r0); o[2 * t + 1] = f2bf(r1);
  }
}

extern "C" void kernel_launch(void* const* d_in, const int* in_sizes, int n_in,
                              void* d_out, int out_size, void* d_ws, size_t ws_size,
                              hipStream_t stream) {
  const float* queries = (const float*)d_in[0];
  const float* keys    = (const float*)d_in[1];
  const int*   qlen    = (const int*)d_in[2];
  const float* cWq = (const float*)d_in[3],  *cbq = (const float*)d_in[4];
  const float* cWk = (const float*)d_in[5],  *cbk = (const float*)d_in[6];
  const float* cWv = (const float*)d_in[7],  *cbv = (const float*)d_in[8];
  const float* cWo = (const float*)d_in[9],  *cbo = (const float*)d_in[10];
  const float* sWq = (const float*)d_in[11], *sbq = (const float*)d_in[12];
  const float* sWk = (const float*)d_in[13], *sbk = (const float*)d_in[14];
  const float* sWv = (const float*)d_in[15], *sbv = (const float*)d_in[16];
  const float* sWo = (const float*)d_in[17], *sbo = (const float*)d_in[18];
  const float* Wf  = (const float*)d_in[19], *bfb = (const float*)d_in[20];
  const float* g_cross = (const float*)d_in[21], *b_cross = (const float*)d_in[22];
  const float* g_ffn   = (const float*)d_in[23], *b_ffn   = (const float*)d_in[24];
  const float* g_self  = (const float*)d_in[25], *b_self  = (const float*)d_in[26];

  float* out_q = (float*)d_out;
  float* out_w = out_q + (long)BB * SLQ * EE;

  u16* ws = (u16*)d_ws;
  u16* S     = ws;                               // 67,108,864 u16
  u16* Qc    = S   + (long)BB * HH * SLQ * SLK;
  u16* Kc    = Qc  + (long)BB * HH * SLQ * HD;
  u16* Vt    = Kc  + (long)BB * HH * SLK * HD;
  u16* q0    = Vt  + (long)BB * HH * SLK * HD;
  u16* keysb = q0  + (long)BB * SLQ * EE;
  u16* attn  = keysb + (long)BB * SLK * EE;
  u16* proj  = attn + (long)BB * SLQ * EE;
  u16* q1    = proj + (long)BB * SLQ * EE;
  u16* fbuf  = q1  + (long)BB * SLQ * EE;
  u16* q2    = fbuf + (long)BB * SLQ * EE;
  u16* Wb    = q2  + (long)BB * SLQ * EE;
  const long WSLOT = (long)EE * EE;
  u16*    Cpb  = Wb + 9 * WSLOT;                  // cross O partials bf16: 32768*4*64
  float2* stat = (float2*)(Cpb + 8388608);        // 32768 float2

  // self partials overlay S (dead after pv_cross)
  u16*    OpS = S;                                // 32768*4*64 bf16
  float2* mlS = (float2*)(S + 8388608);           // 32768*4 float2

  u16* bWq = Wb + 0 * WSLOT; u16* bWk = Wb + 1 * WSLOT; u16* bWv = Wb + 2 * WSLOT;
  u16* bWo = Wb + 3 * WSLOT; u16* bsWq = Wb + 4 * WSLOT; u16* bsWk = Wb + 5 * WSLOT;
  u16* bsWv = Wb + 6 * WSLOT; u16* bsWo = Wb + 7 * WSLOT; u16* bWf = Wb + 8 * WSLOT;

  dim3 blk(256);
  const int MQ = BB * SLQ;   // 4096
  const int MK = BB * SLK;   // 8192

  cvt_all<<<dim3(3072 + 9 * 128), blk, 0, stream>>>(
      queries, keys, qlen, cWq, cWk, cWv, cWo, sWq, sWk, sWv, sWo, Wf, q0, keysb, Wb);

  // cross Q projection
  gemm_nt<64, 64, 1, 2><<<dim3(EE / 64, MQ / 64, 1), blk, 0, stream>>>(
      q0, bWq, cbq, Qc, MQ, EE, EE, EE, EE, 0, 0, 0, 0, 1.0f, SLQ, qlen);
  // cross K+V projections in one dispatch
  gemm_proj<64, 64, 0, 2><<<dim3(EE / 64, MK / 64, 2), blk, 0, stream>>>(
      keysb, bWk, bWv, nullptr, cbk, cbv, nullptr, Kc, Vt, nullptr, MK, EE, SLK, qlen);

  // S = Q K^T * 1/8
  gemm_nt<128, 128, 0, 1><<<dim3(SLK / 128, SLQ / 128, BB * HH), blk, 0, stream>>>(
      Qc, Kc, nullptr, S, SLQ, SLK, HD, HD, HD, SLK,
      (long)SLQ * HD, (long)SLK * HD, (long)SLQ * SLK, 0.125f, 0, qlen);

  softmax_stats_wmean<<<dim3(BB * SLQ), blk, 0, stream>>>(S, out_w, stat, qlen);

  pv_cross<<<dim3(16, 32, 4), blk, 0, stream>>>(S, Vt, stat, Cpb, qlen);
  pv_combine_cross<<<dim3(2048), blk, 0, stream>>>(Cpb, stat, attn, qlen);

  gemm_nt<64, 64, 0, 2><<<dim3(EE / 64, MQ / 64, 1), blk, 0, stream>>>(
      attn, bWo, cbo, proj, MQ, EE, EE, EE, EE, EE, 0, 0, 0, 1.0f, SLQ, qlen);

  silu_ln_kernel<0><<<dim3(MQ), blk, 0, stream>>>(proj, q0, g_cross, b_cross, qlen, q1, 2);

  gemm_nt<64, 64, 0, 2><<<dim3(EE / 64, MQ / 64, 1), blk, 0, stream>>>(
      q1, bWf, bfb, fbuf, MQ, EE, EE, EE, EE, EE, 0, 0, 0, 1.0f, SLQ, qlen);

  silu_ln_kernel<0><<<dim3(MQ), blk, 0, stream>>>(q1, fbuf, g_ffn, b_ffn, qlen, q2, 1);

  // self Q/K/V projections in one dispatch
  gemm_proj<64, 64, 2, 3><<<dim3(EE / 64, MQ / 64, 3), blk, 0, stream>>>(
      q2, bsWq, bsWk, bsWv, sbq, sbk, sbv, Qc, Kc, Vt, MQ, EE, SLQ, qlen);

  // fused self attention (partials overlay S)
  self_flash_chunk<<<dim3(16, 32, 4), blk, 0, stream>>>(Qc, Kc, Vt, OpS, mlS, qlen);
  self_combine<<<dim3(2048), blk, 0, stream>>>(OpS, mlS, attn, qlen);

  gemm_nt<64, 64, 0, 2><<<dim3(EE / 64, MQ / 64, 1), blk, 0, stream>>>(
      attn, bsWo, sbo, proj, MQ, EE, EE, EE, EE, EE, 0, 0, 0, 1.0f, SLQ, qlen);

  silu_ln_kernel<1><<<dim3(MQ), blk, 0, stream>>>(q2, proj, g_self, b_self, qlen, out_q, 1);
}